// Round 1
// baseline (1883.584 us; speedup 1.0000x reference)
//
#include <hip/hip_runtime.h>
#include <hip/hip_bf16.h>
#include <stdint.h>

#define DEV __device__ __forceinline__

constexpr int BATCH = 8;

constexpr int il2(int n) { return (n <= 1) ? 0 : 1 + il2(n / 2); }

DEV float ldy(const float* p, int i) { return p[i]; }
DEV float ldy(const __hip_bfloat16* p, int i) { return __bfloat162float(p[i]); }
DEV void sty(float* p, int i, float v) { p[i] = v; }
DEV void sty(__hip_bfloat16* p, int i, float v) { p[i] = __float2bfloat16(v); }

// ---------------- mask prep: int32 mask -> uint8 m0, count actives ----------------
__global__ __launch_bounds__(256) void mask_prep_k(const int* __restrict__ msk,
                                                   uint8_t* __restrict__ m0,
                                                   int* __restrict__ cnt) {
  int idx = blockIdx.x * 256 + threadIdx.x;  // one int4 (4 voxels) per thread
  int4 v = ((const int4*)msk)[idx];
  uint32_t o = (v.x ? 1u : 0u) | (v.y ? 256u : 0u) | (v.z ? 65536u : 0u) | (v.w ? 16777216u : 0u);
  ((uint32_t*)m0)[idx] = o;
  int c = (v.x != 0) + (v.y != 0) + (v.z != 0) + (v.w != 0);
#pragma unroll
  for (int off = 32; off >= 1; off >>= 1) c += __shfl_xor(c, off);
  if ((threadIdx.x & 63) == 0) atomicAdd(cnt, c);
}

// ---------------- mask downsample 2x (max of 8 children) + count ----------------
template <int Dout>
__global__ __launch_bounds__(256) void down_mask_k(const uint8_t* __restrict__ mi,
                                                   uint8_t* __restrict__ mo,
                                                   int* __restrict__ cnt) {
  constexpr int Din = Dout * 2;
  constexpr int total = BATCH * Dout * Dout * Dout;
  constexpr int LD = il2(Dout);
  int idx = blockIdx.x * 256 + threadIdx.x;
  int act = 0;
  if (idx < total) {
    int x = idx & (Dout - 1);
    int y = (idx >> LD) & (Dout - 1);
    int z = (idx >> (2 * LD)) & (Dout - 1);
    int b = idx >> (3 * LD);
#pragma unroll
    for (int dz = 0; dz < 2; dz++)
#pragma unroll
      for (int dy = 0; dy < 2; dy++)
#pragma unroll
        for (int dx = 0; dx < 2; dx++)
          act |= mi[((b * Din + 2 * z + dz) * Din + 2 * y + dy) * Din + 2 * x + dx];
    mo[idx] = (uint8_t)(act ? 1 : 0);
  }
  unsigned long long bal = __ballot(idx < total && act);
  if ((threadIdx.x & 63) == 0) atomicAdd(cnt, (int)__popcll(bal));
}

// ---------------- layer 0 conv: Cin=1, Cout=2, stride 1, D=128, LDS tiled ----------------
template <typename Tout>
__global__ __launch_bounds__(512) void conv0_k(const float* __restrict__ x,
                                               const uint8_t* __restrict__ m0,
                                               const float* __restrict__ w,  // [27][1][2]
                                               Tout* __restrict__ y0,
                                               float* __restrict__ partials) {  // [blocks][4]
  __shared__ float sx[1000];  // 10x10x10
  int blk = blockIdx.x;
  int tx0 = (blk & 15) * 8, ty0 = ((blk >> 4) & 15) * 8, tz0 = ((blk >> 8) & 15) * 8, b = blk >> 12;
  int tid = threadIdx.x;
  for (int idx = tid; idx < 1000; idx += 512) {
    int lz = idx / 100, r = idx - lz * 100, ly = r / 10, lx = r - ly * 10;
    int gz = tz0 + lz - 1, gy = ty0 + ly - 1, gx = tx0 + lx - 1;
    float val = 0.f;
    if ((unsigned)gz < 128u && (unsigned)gy < 128u && (unsigned)gx < 128u) {
      int gi = ((b * 128 + gz) * 128 + gy) * 128 + gx;
      if (m0[gi]) val = x[gi];
    }
    sx[idx] = val;
  }
  __syncthreads();
  int lx = tid & 7, ly = (tid >> 3) & 7, lz = tid >> 6;
  int v = ((b * 128 + tz0 + lz) * 128 + ty0 + ly) * 128 + tx0 + lx;
  float a0 = 0.f, a1 = 0.f;
  if (m0[v]) {
#pragma unroll
    for (int dz = 0; dz < 3; dz++)
#pragma unroll
      for (int dy = 0; dy < 3; dy++)
#pragma unroll
        for (int dx = 0; dx < 3; dx++) {
          float s = sx[(lz + dz) * 100 + (ly + dy) * 10 + (lx + dx)];
          const float* wp = w + ((dz * 3 + dy) * 3 + dx) * 2;
          a0 = fmaf(s, wp[0], a0);
          a1 = fmaf(s, wp[1], a1);
        }
  }
  sty(y0, 2 * v, a0);
  sty(y0, 2 * v + 1, a1);
  // stats: per-block sum/sumsq per channel (deterministic)
  float s0 = a0, q0 = a0 * a0, s1 = a1, q1 = a1 * a1;
#pragma unroll
  for (int off = 32; off >= 1; off >>= 1) {
    s0 += __shfl_xor(s0, off);
    q0 += __shfl_xor(q0, off);
    s1 += __shfl_xor(s1, off);
    q1 += __shfl_xor(q1, off);
  }
  __shared__ float sm[8][4];
  int wave = tid >> 6;
  if ((tid & 63) == 0) {
    sm[wave][0] = s0;
    sm[wave][1] = q0;
    sm[wave][2] = s1;
    sm[wave][3] = q1;
  }
  __syncthreads();
  if (tid < 4) {
    float t = 0.f;
#pragma unroll
    for (int wv = 0; wv < 8; wv++) t += sm[wv][tid];
    partials[blk * 4 + tid] = t;
  }
}

// ---------------- generic stride-2 conv, BN+ReLU folded into input load ----------------
template <int Din, int Cin, int Cout, typename Tin, typename Tout>
__global__ __launch_bounds__(256) void conv_s2_k(const Tin* __restrict__ yin,
                                                 const uint8_t* __restrict__ mi,
                                                 const uint8_t* __restrict__ mo,
                                                 const float* __restrict__ ssin,  // [2*Cin]
                                                 const float* __restrict__ w,     // [27][Cin][Cout]
                                                 Tout* __restrict__ yout,
                                                 float* __restrict__ partials) {  // [blocks][2*Cout]
  constexpr int Dout = Din / 2;
  constexpr int LD = il2(Dout);
  constexpr int LC = il2(Cout);
  int tid = threadIdx.x;
  int lin = blockIdx.x * 256 + tid;
  int co = lin & (Cout - 1);
  int v = lin >> LC;
  int x = v & (Dout - 1);
  int y = (v >> LD) & (Dout - 1);
  int z = (v >> (2 * LD)) & (Dout - 1);
  int b = v >> (3 * LD);
  float acc = 0.f;
  if (mo[v]) {
    for (int dz = 0; dz < 3; dz++) {
      int iz = 2 * z + dz - 1;
      if ((unsigned)iz >= (unsigned)Din) continue;
      for (int dy = 0; dy < 3; dy++) {
        int iy = 2 * y + dy - 1;
        if ((unsigned)iy >= (unsigned)Din) continue;
        for (int dx = 0; dx < 3; dx++) {
          int ix = 2 * x + dx - 1;
          if ((unsigned)ix >= (unsigned)Din) continue;
          int gi = ((b * Din + iz) * Din + iy) * Din + ix;
          if (mi[gi]) {
            const Tin* yp = yin + (size_t)gi * Cin;
            const float* wp = w + ((dz * 3 + dy) * 3 + dx) * Cin * Cout + co;
#pragma unroll
            for (int ci = 0; ci < Cin; ci++) {
              float val = fmaxf(fmaf(ldy(yp, ci), ssin[2 * ci], ssin[2 * ci + 1]), 0.f);
              acc = fmaf(val, wp[ci * Cout], acc);
            }
          }
        }
      }
    }
  }
  sty(yout, lin, acc);
  // stats
  float s = acc, q = acc * acc;
#pragma unroll
  for (int off = 32; off >= Cout; off >>= 1) {
    s += __shfl_xor(s, off);
    q += __shfl_xor(q, off);
  }
  __shared__ float sm[4][2 * Cout];
  int wave = tid >> 6, lane = tid & 63;
  if (lane < Cout) {
    sm[wave][2 * lane] = s;
    sm[wave][2 * lane + 1] = q;
  }
  __syncthreads();
  if (tid < 2 * Cout)
    partials[blockIdx.x * 2 * Cout + tid] = sm[0][tid] + sm[1][tid] + sm[2][tid] + sm[3][tid];
}

// ---------------- stat reduce: partials -> per-channel (scale, shift) ----------------
template <int Cout>
__global__ __launch_bounds__(256) void stats_k(const float* __restrict__ partials, int nblocks,
                                               const int* __restrict__ cnt,
                                               const float* __restrict__ g,
                                               const float* __restrict__ bb,
                                               float* __restrict__ ss) {
  int c = blockIdx.x, tid = threadIdx.x;
  float s = 0.f, q = 0.f;
  for (int i = tid; i < nblocks; i += 256) {
    s += partials[i * 2 * Cout + 2 * c];
    q += partials[i * 2 * Cout + 2 * c + 1];
  }
  __shared__ float S[256], Q[256];
  S[tid] = s;
  Q[tid] = q;
  __syncthreads();
  for (int st = 128; st > 0; st >>= 1) {
    if (tid < st) {
      S[tid] += S[tid + st];
      Q[tid] += Q[tid + st];
    }
    __syncthreads();
  }
  if (tid == 0) {
    float n = fmaxf((float)cnt[0], 1.f);
    float mean = S[0] / n;
    float var = Q[0] / n - mean * mean;
    float scale = g[c] * rsqrtf(var + 1e-5f);
    ss[2 * c] = scale;
    ss[2 * c + 1] = bb[c] - mean * scale;
  }
}

// ---------------- final sparse max pool 3x3x3 s2 pad1: 4^3 -> 2^3 ----------------
__global__ __launch_bounds__(512) void pool_k(const float* __restrict__ y5,
                                              const uint8_t* __restrict__ m5,
                                              const uint8_t* __restrict__ m6,
                                              const float* __restrict__ ss,
                                              float* __restrict__ out) {
  int b = blockIdx.x, tid = threadIdx.x;
  int c = tid & 63, s = tid >> 6;
  int qx = s & 1, qy = (s >> 1) & 1, qz = (s >> 2) & 1;
  int ov = ((b * 2 + qz) * 2 + qy) * 2 + qx;
  float scale = ss[2 * c], shift = ss[2 * c + 1];
  float mx = 0.f;
  for (int dz = 0; dz < 3; dz++) {
    int iz = 2 * qz + dz - 1;
    if ((unsigned)iz >= 4u) continue;
    for (int dy = 0; dy < 3; dy++) {
      int iy = 2 * qy + dy - 1;
      if ((unsigned)iy >= 4u) continue;
      for (int dx = 0; dx < 3; dx++) {
        int ix = 2 * qx + dx - 1;
        if ((unsigned)ix >= 4u) continue;
        int gi = ((b * 4 + iz) * 4 + iy) * 4 + ix;
        if (m5[gi]) {
          float val = fmaxf(fmaf(y5[gi * 64 + c], scale, shift), 0.f);
          mx = fmaxf(mx, val);
        }
      }
    }
  }
  out[ov * 64 + c] = m6[ov] ? mx : 0.f;
}

extern "C" void kernel_launch(void* const* d_in, const int* in_sizes, int n_in,
                              void* d_out, int out_size, void* d_ws, size_t ws_size,
                              hipStream_t stream) {
  const float* x = (const float*)d_in[0];
  const int* msk = (const int*)d_in[1];
  const float *w[6], *g[6], *bb[6];
  for (int i = 0; i < 6; i++) {
    w[i] = (const float*)d_in[2 + 3 * i];
    g[i] = (const float*)d_in[3 + 3 * i];
    bb[i] = (const float*)d_in[4 + 3 * i];
  }

  // element counts
  const size_t Y0E = 33554432, Y1E = 8388608;  // elems
  auto layout_need = [&](bool slim) -> size_t {
    size_t o = 0;
    auto A = [&](size_t bytes) { o = (o + bytes + 255) & ~(size_t)255; };
    A(Y0E * (slim ? 2 : 4));
    A(Y1E * (slim ? 2 : 4));
    A(8388608);   // y2
    A(2097152);   // y3
    A(524288);    // y4
    A(131072);    // y5
    A(16777216);  // m0
    A(2097152);   // m1
    A(262144);    // m2
    A(32768);     // m3
    A(4096);      // m4
    A(512);       // m5
    A(64);        // m6
    A(1 << 20);   // partials
    A(3072);      // ss
    A(32);        // cnt
    return o;
  };
  bool slim = ws_size < layout_need(false);
  if (slim && ws_size < layout_need(true)) return;  // cannot run safely

  char* ws = (char*)d_ws;
  size_t o = 0;
  auto A = [&](size_t bytes) -> char* {
    char* p = ws + o;
    o = (o + bytes + 255) & ~(size_t)255;
    return p;
  };
  char* p_y0 = A(Y0E * (slim ? 2 : 4));
  char* p_y1 = A(Y1E * (slim ? 2 : 4));
  float* y2 = (float*)A(8388608);
  float* y3 = (float*)A(2097152);
  float* y4 = (float*)A(524288);
  float* y5 = (float*)A(131072);
  uint8_t* m0 = (uint8_t*)A(16777216);
  uint8_t* m1 = (uint8_t*)A(2097152);
  uint8_t* m2 = (uint8_t*)A(262144);
  uint8_t* m3 = (uint8_t*)A(32768);
  uint8_t* m4 = (uint8_t*)A(4096);
  uint8_t* m5 = (uint8_t*)A(512);
  uint8_t* m6 = (uint8_t*)A(64);
  float* part = (float*)A(1 << 20);
  float* ss = (float*)A(3072);
  int* cnt = (int*)A(32);

  hipMemsetAsync(cnt, 0, 32, stream);
  mask_prep_k<<<16384, 256, 0, stream>>>(msk, m0, cnt + 0);
  down_mask_k<64><<<8192, 256, 0, stream>>>(m0, m1, cnt + 1);
  down_mask_k<32><<<1024, 256, 0, stream>>>(m1, m2, cnt + 2);
  down_mask_k<16><<<128, 256, 0, stream>>>(m2, m3, cnt + 3);
  down_mask_k<8><<<16, 256, 0, stream>>>(m3, m4, cnt + 4);
  down_mask_k<4><<<2, 256, 0, stream>>>(m4, m5, cnt + 5);
  down_mask_k<2><<<1, 256, 0, stream>>>(m5, m6, cnt + 6);

  if (!slim) {
    float* y0 = (float*)p_y0;
    float* y1 = (float*)p_y1;
    conv0_k<float><<<32768, 512, 0, stream>>>(x, m0, w[0], y0, part);
    stats_k<2><<<2, 256, 0, stream>>>(part, 32768, cnt + 0, g[0], bb[0], ss + 0);
    conv_s2_k<128, 2, 4, float, float><<<32768, 256, 0, stream>>>(y0, m0, m1, ss + 0, w[1], y1, part);
    stats_k<4><<<4, 256, 0, stream>>>(part, 32768, cnt + 1, g[1], bb[1], ss + 128);
    conv_s2_k<64, 4, 8, float, float><<<8192, 256, 0, stream>>>(y1, m1, m2, ss + 128, w[2], y2, part);
  } else {
    __hip_bfloat16* y0 = (__hip_bfloat16*)p_y0;
    __hip_bfloat16* y1 = (__hip_bfloat16*)p_y1;
    conv0_k<__hip_bfloat16><<<32768, 512, 0, stream>>>(x, m0, w[0], y0, part);
    stats_k<2><<<2, 256, 0, stream>>>(part, 32768, cnt + 0, g[0], bb[0], ss + 0);
    conv_s2_k<128, 2, 4, __hip_bfloat16, __hip_bfloat16><<<32768, 256, 0, stream>>>(y0, m0, m1, ss + 0, w[1], y1, part);
    stats_k<4><<<4, 256, 0, stream>>>(part, 32768, cnt + 1, g[1], bb[1], ss + 128);
    conv_s2_k<64, 4, 8, __hip_bfloat16, float><<<8192, 256, 0, stream>>>(y1, m1, m2, ss + 128, w[2], y2, part);
  }
  stats_k<8><<<8, 256, 0, stream>>>(part, 8192, cnt + 2, g[2], bb[2], ss + 256);
  conv_s2_k<32, 8, 16, float, float><<<2048, 256, 0, stream>>>(y2, m2, m3, ss + 256, w[3], y3, part);
  stats_k<16><<<16, 256, 0, stream>>>(part, 2048, cnt + 3, g[3], bb[3], ss + 384);
  conv_s2_k<16, 16, 32, float, float><<<512, 256, 0, stream>>>(y3, m3, m4, ss + 384, w[4], y4, part);
  stats_k<32><<<32, 256, 0, stream>>>(part, 512, cnt + 4, g[4], bb[4], ss + 512);
  conv_s2_k<8, 32, 64, float, float><<<128, 256, 0, stream>>>(y4, m4, m5, ss + 512, w[5], y5, part);
  stats_k<64><<<64, 256, 0, stream>>>(part, 128, cnt + 5, g[5], bb[5], ss + 640);
  pool_k<<<8, 512, 0, stream>>>(y5, m5, m6, ss + 640, (float*)d_out);
}

// Round 2
// 686.555 us; speedup vs baseline: 2.7435x; 2.7435x over previous
//
#include <hip/hip_runtime.h>
#include <hip/hip_bf16.h>
#include <stdint.h>

#define DEV __device__ __forceinline__

constexpr int BATCH = 8;

constexpr int il2(int n) { return (n <= 1) ? 0 : 1 + il2(n / 2); }

DEV float ldy(const float* p, int i) { return p[i]; }
DEV float ldy(const __hip_bfloat16* p, int i) { return __bfloat162float(p[i]); }
DEV void sty(float* p, int i, float v) { p[i] = v; }
DEV void sty(__hip_bfloat16* p, int i, float v) { p[i] = __float2bfloat16(v); }

// ---------------- mask prep: int32 mask -> uint8 m0 (pure convert, no atomics) ----------------
__global__ __launch_bounds__(256) void mask_prep_k(const int* __restrict__ msk,
                                                   uint8_t* __restrict__ m0) {
  int idx = blockIdx.x * 256 + threadIdx.x;  // one int4 (4 voxels) per thread
  int4 v = ((const int4*)msk)[idx];
  uint32_t o = (v.x ? 1u : 0u) | (v.y ? 256u : 0u) | (v.z ? 65536u : 0u) | (v.w ? 16777216u : 0u);
  ((uint32_t*)m0)[idx] = o;
}

// ---------------- mask downsample 2x (max of 8 children) ----------------
template <int Dout>
__global__ __launch_bounds__(256) void down_mask_k(const uint8_t* __restrict__ mi,
                                                   uint8_t* __restrict__ mo) {
  constexpr int Din = Dout * 2;
  constexpr int total = BATCH * Dout * Dout * Dout;
  constexpr int LD = il2(Dout);
  int idx = blockIdx.x * 256 + threadIdx.x;
  if (idx >= total) return;
  int x = idx & (Dout - 1);
  int y = (idx >> LD) & (Dout - 1);
  int z = (idx >> (2 * LD)) & (Dout - 1);
  int b = idx >> (3 * LD);
  int act = 0;
#pragma unroll
  for (int dz = 0; dz < 2; dz++)
#pragma unroll
    for (int dy = 0; dy < 2; dy++)
#pragma unroll
      for (int dx = 0; dx < 2; dx++)
        act |= mi[((b * Din + 2 * z + dz) * Din + 2 * y + dy) * Din + 2 * x + dx];
  mo[idx] = (uint8_t)(act ? 1 : 0);
}

// ---------------- layer 0 conv: Cin=1, Cout=2, stride 1, D=128, LDS tiled ----------------
// partials record: [s0, q0, s1, q1, active_count] per block (stride 5)
__global__ __launch_bounds__(512) void conv0_k(const float* __restrict__ x,
                                               const uint8_t* __restrict__ m0,
                                               const float* __restrict__ w,  // [27][1][2]
                                               __hip_bfloat16* __restrict__ y0,
                                               float* __restrict__ partials) {
  __shared__ float sx[1000];  // 10x10x10
  int blk = blockIdx.x;
  int tx0 = (blk & 15) * 8, ty0 = ((blk >> 4) & 15) * 8, tz0 = ((blk >> 8) & 15) * 8, b = blk >> 12;
  int tid = threadIdx.x;
  for (int idx = tid; idx < 1000; idx += 512) {
    int lz = idx / 100, r = idx - lz * 100, ly = r / 10, lx = r - ly * 10;
    int gz = tz0 + lz - 1, gy = ty0 + ly - 1, gx = tx0 + lx - 1;
    float val = 0.f;
    if ((unsigned)gz < 128u && (unsigned)gy < 128u && (unsigned)gx < 128u) {
      int gi = ((b * 128 + gz) * 128 + gy) * 128 + gx;
      if (m0[gi]) val = x[gi];
    }
    sx[idx] = val;
  }
  __syncthreads();
  int lx = tid & 7, ly = (tid >> 3) & 7, lz = tid >> 6;
  int v = ((b * 128 + tz0 + lz) * 128 + ty0 + ly) * 128 + tx0 + lx;
  bool act = m0[v] != 0;
  float a0 = 0.f, a1 = 0.f;
  if (act) {
#pragma unroll
    for (int dz = 0; dz < 3; dz++)
#pragma unroll
      for (int dy = 0; dy < 3; dy++)
#pragma unroll
        for (int dx = 0; dx < 3; dx++) {
          float s = sx[(lz + dz) * 100 + (ly + dy) * 10 + (lx + dx)];
          const float* wp = w + ((dz * 3 + dy) * 3 + dx) * 2;
          a0 = fmaf(s, wp[0], a0);
          a1 = fmaf(s, wp[1], a1);
        }
  }
  __hip_bfloat162 pk;
  pk.x = __float2bfloat16(a0);
  pk.y = __float2bfloat16(a1);
  ((__hip_bfloat162*)y0)[v] = pk;
  // stats: per-block sum/sumsq per channel + active count (deterministic)
  float s0 = a0, q0 = a0 * a0, s1 = a1, q1 = a1 * a1;
#pragma unroll
  for (int off = 32; off >= 1; off >>= 1) {
    s0 += __shfl_xor(s0, off);
    q0 += __shfl_xor(q0, off);
    s1 += __shfl_xor(s1, off);
    q1 += __shfl_xor(q1, off);
  }
  unsigned long long bal = __ballot(act);
  __shared__ float sm[8][5];
  int wave = tid >> 6;
  if ((tid & 63) == 0) {
    sm[wave][0] = s0;
    sm[wave][1] = q0;
    sm[wave][2] = s1;
    sm[wave][3] = q1;
    sm[wave][4] = (float)__popcll(bal);
  }
  __syncthreads();
  if (tid < 5) {
    float t = 0.f;
#pragma unroll
    for (int wv = 0; wv < 8; wv++) t += sm[wv][tid];
    partials[blk * 5 + tid] = t;
  }
}

// ---------------- generic stride-2 conv, BN+ReLU folded into input load ----------------
// partials record: [s_c, q_c]*Cout + [active_count]  (stride 2*Cout+1)
template <int Din, int Cin, int Cout, typename Tin, typename Tout>
__global__ __launch_bounds__(256) void conv_s2_k(const Tin* __restrict__ yin,
                                                 const uint8_t* __restrict__ mi,
                                                 const uint8_t* __restrict__ mo,
                                                 const float* __restrict__ ssin,  // [2*Cin]
                                                 const float* __restrict__ w,     // [27][Cin][Cout]
                                                 Tout* __restrict__ yout,
                                                 float* __restrict__ partials) {
  constexpr int Dout = Din / 2;
  constexpr int LD = il2(Dout);
  constexpr int LC = il2(Cout);
  constexpr int REC = 2 * Cout + 1;
  int tid = threadIdx.x;
  int lin = blockIdx.x * 256 + tid;
  int co = lin & (Cout - 1);
  int v = lin >> LC;
  int x = v & (Dout - 1);
  int y = (v >> LD) & (Dout - 1);
  int z = (v >> (2 * LD)) & (Dout - 1);
  int b = v >> (3 * LD);
  bool act = mo[v] != 0;
  float acc = 0.f;
  if (act) {
    for (int dz = 0; dz < 3; dz++) {
      int iz = 2 * z + dz - 1;
      if ((unsigned)iz >= (unsigned)Din) continue;
      for (int dy = 0; dy < 3; dy++) {
        int iy = 2 * y + dy - 1;
        if ((unsigned)iy >= (unsigned)Din) continue;
        for (int dx = 0; dx < 3; dx++) {
          int ix = 2 * x + dx - 1;
          if ((unsigned)ix >= (unsigned)Din) continue;
          int gi = ((b * Din + iz) * Din + iy) * Din + ix;
          if (mi[gi]) {
            const Tin* yp = yin + (size_t)gi * Cin;
            const float* wp = w + ((dz * 3 + dy) * 3 + dx) * Cin * Cout + co;
#pragma unroll
            for (int ci = 0; ci < Cin; ci++) {
              float val = fmaxf(fmaf(ldy(yp, ci), ssin[2 * ci], ssin[2 * ci + 1]), 0.f);
              acc = fmaf(val, wp[ci * Cout], acc);
            }
          }
        }
      }
    }
  }
  sty(yout, lin, acc);
  // stats
  float s = acc, q = acc * acc;
#pragma unroll
  for (int off = 32; off >= Cout; off >>= 1) {
    s += __shfl_xor(s, off);
    q += __shfl_xor(q, off);
  }
  unsigned long long bal = __ballot(act && co == 0);
  __shared__ float sm[4][REC];
  int wave = tid >> 6, lane = tid & 63;
  if (lane < Cout) {
    sm[wave][2 * lane] = s;
    sm[wave][2 * lane + 1] = q;
  }
  if (lane == 0) sm[wave][2 * Cout] = (float)__popcll(bal);
  __syncthreads();
  if (tid < REC)
    partials[(size_t)blockIdx.x * REC + tid] = sm[0][tid] + sm[1][tid] + sm[2][tid] + sm[3][tid];
}

// ---------------- stat reduce: partials -> per-channel (scale, shift) ----------------
template <int Cout>
__global__ __launch_bounds__(256) void stats_k(const float* __restrict__ partials, int nblocks,
                                               const float* __restrict__ g,
                                               const float* __restrict__ bb,
                                               float* __restrict__ ss) {
  constexpr int REC = 2 * Cout + 1;
  int c = blockIdx.x, tid = threadIdx.x;
  float s = 0.f, q = 0.f, n = 0.f;
  for (int i = tid; i < nblocks; i += 256) {
    const float* p = partials + (size_t)i * REC;
    s += p[2 * c];
    q += p[2 * c + 1];
    n += p[2 * Cout];
  }
  __shared__ float S[256], Q[256], N[256];
  S[tid] = s;
  Q[tid] = q;
  N[tid] = n;
  __syncthreads();
  for (int st = 128; st > 0; st >>= 1) {
    if (tid < st) {
      S[tid] += S[tid + st];
      Q[tid] += Q[tid + st];
      N[tid] += N[tid + st];
    }
    __syncthreads();
  }
  if (tid == 0) {
    float cnt = fmaxf(N[0], 1.f);
    float mean = S[0] / cnt;
    float var = Q[0] / cnt - mean * mean;
    float scale = g[c] * rsqrtf(var + 1e-5f);
    ss[2 * c] = scale;
    ss[2 * c + 1] = bb[c] - mean * scale;
  }
}

// ---------------- final sparse max pool 3x3x3 s2 pad1: 4^3 -> 2^3 ----------------
__global__ __launch_bounds__(512) void pool_k(const float* __restrict__ y5,
                                              const uint8_t* __restrict__ m5,
                                              const uint8_t* __restrict__ m6,
                                              const float* __restrict__ ss,
                                              float* __restrict__ out) {
  int b = blockIdx.x, tid = threadIdx.x;
  int c = tid & 63, s = tid >> 6;
  int qx = s & 1, qy = (s >> 1) & 1, qz = (s >> 2) & 1;
  int ov = ((b * 2 + qz) * 2 + qy) * 2 + qx;
  float scale = ss[2 * c], shift = ss[2 * c + 1];
  float mx = 0.f;
  for (int dz = 0; dz < 3; dz++) {
    int iz = 2 * qz + dz - 1;
    if ((unsigned)iz >= 4u) continue;
    for (int dy = 0; dy < 3; dy++) {
      int iy = 2 * qy + dy - 1;
      if ((unsigned)iy >= 4u) continue;
      for (int dx = 0; dx < 3; dx++) {
        int ix = 2 * qx + dx - 1;
        if ((unsigned)ix >= 4u) continue;
        int gi = ((b * 4 + iz) * 4 + iy) * 4 + ix;
        if (m5[gi]) {
          float val = fmaxf(fmaf(y5[gi * 64 + c], scale, shift), 0.f);
          mx = fmaxf(mx, val);
        }
      }
    }
  }
  out[ov * 64 + c] = m6[ov] ? mx : 0.f;
}

extern "C" void kernel_launch(void* const* d_in, const int* in_sizes, int n_in,
                              void* d_out, int out_size, void* d_ws, size_t ws_size,
                              hipStream_t stream) {
  const float* x = (const float*)d_in[0];
  const int* msk = (const int*)d_in[1];
  const float *w[6], *g[6], *bb[6];
  for (int i = 0; i < 6; i++) {
    w[i] = (const float*)d_in[2 + 3 * i];
    g[i] = (const float*)d_in[3 + 3 * i];
    bb[i] = (const float*)d_in[4 + 3 * i];
  }

  char* ws = (char*)d_ws;
  size_t o = 0;
  auto A = [&](size_t bytes) -> char* {
    char* p = ws + o;
    o = (o + bytes + 255) & ~(size_t)255;
    return p;
  };
  __hip_bfloat16* y0 = (__hip_bfloat16*)A(33554432 * 2);  // 64 MB
  __hip_bfloat16* y1 = (__hip_bfloat16*)A(8388608 * 2);   // 16 MB
  float* y2 = (float*)A(8388608);
  float* y3 = (float*)A(2097152);
  float* y4 = (float*)A(524288);
  float* y5 = (float*)A(131072);
  uint8_t* m0 = (uint8_t*)A(16777216);
  uint8_t* m1 = (uint8_t*)A(2097152);
  uint8_t* m2 = (uint8_t*)A(262144);
  uint8_t* m3 = (uint8_t*)A(32768);
  uint8_t* m4 = (uint8_t*)A(4096);
  uint8_t* m5 = (uint8_t*)A(512);
  uint8_t* m6 = (uint8_t*)A(64);
  float* part = (float*)A(2 << 20);
  float* ss = (float*)A(4096);
  if (o > ws_size) return;  // cannot run safely

  mask_prep_k<<<16384, 256, 0, stream>>>(msk, m0);
  down_mask_k<64><<<8192, 256, 0, stream>>>(m0, m1);
  down_mask_k<32><<<1024, 256, 0, stream>>>(m1, m2);
  down_mask_k<16><<<128, 256, 0, stream>>>(m2, m3);
  down_mask_k<8><<<16, 256, 0, stream>>>(m3, m4);
  down_mask_k<4><<<2, 256, 0, stream>>>(m4, m5);
  down_mask_k<2><<<1, 256, 0, stream>>>(m5, m6);

  conv0_k<<<32768, 512, 0, stream>>>(x, m0, w[0], y0, part);
  stats_k<2><<<2, 256, 0, stream>>>(part, 32768, g[0], bb[0], ss + 0);
  conv_s2_k<128, 2, 4, __hip_bfloat16, __hip_bfloat16>
      <<<32768, 256, 0, stream>>>(y0, m0, m1, ss + 0, w[1], y1, part);
  stats_k<4><<<4, 256, 0, stream>>>(part, 32768, g[1], bb[1], ss + 128);
  conv_s2_k<64, 4, 8, __hip_bfloat16, float>
      <<<8192, 256, 0, stream>>>(y1, m1, m2, ss + 128, w[2], y2, part);
  stats_k<8><<<8, 256, 0, stream>>>(part, 8192, g[2], bb[2], ss + 256);
  conv_s2_k<32, 8, 16, float, float>
      <<<2048, 256, 0, stream>>>(y2, m2, m3, ss + 256, w[3], y3, part);
  stats_k<16><<<16, 256, 0, stream>>>(part, 2048, g[3], bb[3], ss + 384);
  conv_s2_k<16, 16, 32, float, float>
      <<<512, 256, 0, stream>>>(y3, m3, m4, ss + 384, w[4], y4, part);
  stats_k<32><<<32, 256, 0, stream>>>(part, 512, g[4], bb[4], ss + 512);
  conv_s2_k<8, 32, 64, float, float>
      <<<128, 256, 0, stream>>>(y4, m4, m5, ss + 512, w[5], y5, part);
  stats_k<64><<<64, 256, 0, stream>>>(part, 128, g[5], bb[5], ss + 640);
  pool_k<<<8, 512, 0, stream>>>(y5, m5, m6, ss + 640, (float*)d_out);
}

// Round 3
// 423.637 us; speedup vs baseline: 4.4462x; 1.6206x over previous
//
#include <hip/hip_runtime.h>
#include <hip/hip_bf16.h>
#include <stdint.h>

#define DEV __device__ __forceinline__

constexpr int BATCH = 8;

constexpr int il2(int n) { return (n <= 1) ? 0 : 1 + il2(n / 2); }

DEV float ldy(const float* p, int i) { return p[i]; }
DEV float ldy(const __hip_bfloat16* p, int i) { return __bfloat162float(p[i]); }
DEV void sty(float* p, size_t i, float v) { p[i] = v; }
DEV void sty(__hip_bfloat16* p, size_t i, float v) { p[i] = __float2bfloat16(v); }

// ---------------- mask prep: int32 mask -> uint8 m0 ----------------
__global__ __launch_bounds__(256) void mask_prep_k(const int* __restrict__ msk,
                                                   uint8_t* __restrict__ m0) {
  int idx = blockIdx.x * 256 + threadIdx.x;  // one int4 (4 voxels) per thread
  int4 v = ((const int4*)msk)[idx];
  uint32_t o = (v.x ? 1u : 0u) | (v.y ? 256u : 0u) | (v.z ? 65536u : 0u) | (v.w ? 16777216u : 0u);
  ((uint32_t*)m0)[idx] = o;
}

// ---------------- mask downsample 2x (max of 8 children) ----------------
template <int Dout>
__global__ __launch_bounds__(256) void down_mask_k(const uint8_t* __restrict__ mi,
                                                   uint8_t* __restrict__ mo) {
  constexpr int Din = Dout * 2;
  constexpr int total = BATCH * Dout * Dout * Dout;
  constexpr int LD = il2(Dout);
  int idx = blockIdx.x * 256 + threadIdx.x;
  if (idx >= total) return;
  int x = idx & (Dout - 1);
  int y = (idx >> LD) & (Dout - 1);
  int z = (idx >> (2 * LD)) & (Dout - 1);
  int b = idx >> (3 * LD);
  int act = 0;
#pragma unroll
  for (int dz = 0; dz < 2; dz++)
#pragma unroll
    for (int dy = 0; dy < 2; dy++)
#pragma unroll
      for (int dx = 0; dx < 2; dx++)
        act |= mi[((b * Din + 2 * z + dz) * Din + 2 * y + dy) * Din + 2 * x + dx];
  mo[idx] = (uint8_t)(act ? 1 : 0);
}

// ---------------- layer 0 conv: Cin=1, Cout=2, stride 1, D=128, LDS tiled ----------------
// partials record: [s0, q0, s1, q1, active_count] per block (stride 5)
__global__ __launch_bounds__(512) void conv0_k(const float* __restrict__ x,
                                               const uint8_t* __restrict__ m0,
                                               const float* __restrict__ w,  // [27][1][2]
                                               __hip_bfloat16* __restrict__ y0,
                                               float* __restrict__ partials) {
  __shared__ float sx[1000];  // 10x10x10
  int blk = blockIdx.x;
  int tx0 = (blk & 15) * 8, ty0 = ((blk >> 4) & 15) * 8, tz0 = ((blk >> 8) & 15) * 8, b = blk >> 12;
  int tid = threadIdx.x;
  for (int idx = tid; idx < 1000; idx += 512) {
    int lz = idx / 100, r = idx - lz * 100, ly = r / 10, lx = r - ly * 10;
    int gz = tz0 + lz - 1, gy = ty0 + ly - 1, gx = tx0 + lx - 1;
    float val = 0.f;
    if ((unsigned)gz < 128u && (unsigned)gy < 128u && (unsigned)gx < 128u) {
      int gi = ((b * 128 + gz) * 128 + gy) * 128 + gx;
      if (m0[gi]) val = x[gi];
    }
    sx[idx] = val;
  }
  __syncthreads();
  int lx = tid & 7, ly = (tid >> 3) & 7, lz = tid >> 6;
  int v = ((b * 128 + tz0 + lz) * 128 + ty0 + ly) * 128 + tx0 + lx;
  bool act = m0[v] != 0;
  float a0 = 0.f, a1 = 0.f;
  if (act) {
#pragma unroll
    for (int dz = 0; dz < 3; dz++)
#pragma unroll
      for (int dy = 0; dy < 3; dy++)
#pragma unroll
        for (int dx = 0; dx < 3; dx++) {
          float s = sx[(lz + dz) * 100 + (ly + dy) * 10 + (lx + dx)];
          const float* wp = w + ((dz * 3 + dy) * 3 + dx) * 2;
          a0 = fmaf(s, wp[0], a0);
          a1 = fmaf(s, wp[1], a1);
        }
  }
  __hip_bfloat162 pk;
  pk.x = __float2bfloat16(a0);
  pk.y = __float2bfloat16(a1);
  ((__hip_bfloat162*)y0)[v] = pk;
  float s0 = a0, q0 = a0 * a0, s1 = a1, q1 = a1 * a1;
#pragma unroll
  for (int off = 32; off >= 1; off >>= 1) {
    s0 += __shfl_xor(s0, off);
    q0 += __shfl_xor(q0, off);
    s1 += __shfl_xor(s1, off);
    q1 += __shfl_xor(q1, off);
  }
  unsigned long long bal = __ballot(act);
  __shared__ float sm[8][5];
  int wave = tid >> 6;
  if ((tid & 63) == 0) {
    sm[wave][0] = s0;
    sm[wave][1] = q0;
    sm[wave][2] = s1;
    sm[wave][3] = q1;
    sm[wave][4] = (float)__popcll(bal);
  }
  __syncthreads();
  if (tid < 5) {
    float t = 0.f;
#pragma unroll
    for (int wv = 0; wv < 8; wv++) t += sm[wv][tid];
    partials[blk * 5 + tid] = t;
  }
}

// ---------------- LDS-tiled stride-2 conv, BN+ReLU+mask folded at staging ----------------
// Output tile: 8 x 8 x TZ voxels, one thread per voxel, all Cout in registers.
// Input tile (zero-padded, masked, BN'd): 17 x 17 x (2*TZ+1) x Cin floats in LDS.
// partials record: [s_c, q_c]*Cout + [active_count]  (stride 2*Cout+1)
template <int Din, int Cin, int Cout, int TZ, typename Tin, typename Tout>
__global__ __launch_bounds__(512) void conv_tile_k(const Tin* __restrict__ yin,
                                                   const uint8_t* __restrict__ mi,
                                                   const uint8_t* __restrict__ mo,
                                                   const float* __restrict__ ssin,  // [2*Cin]
                                                   const float* __restrict__ w,     // [27][Cin][Cout]
                                                   Tout* __restrict__ yout,
                                                   float* __restrict__ partials) {
  constexpr int Dout = Din / 2;
  constexpr int NT = 64 * TZ;       // threads
  constexpr int IZ = 2 * TZ + 1;    // input tile depth
  constexpr int NS = 289 * IZ;      // input tile sites (17*17*IZ)
  constexpr int TXN = Dout / 8;
  constexpr int TZN = Dout / TZ;
  constexpr int LTX = il2(TXN);
  constexpr int LTZ = il2(TZN);
  constexpr int REC = 2 * Cout + 1;
  __shared__ float sx[NS * Cin];
  __shared__ float sm[TZ][REC];

  int tid = threadIdx.x;
  int blk = blockIdx.x;
  int tx0 = (blk & (TXN - 1)) * 8;
  int ty0 = ((blk >> LTX) & (TXN - 1)) * 8;
  int tz0 = ((blk >> (2 * LTX)) & (TZN - 1)) * TZ;
  int b = blk >> (2 * LTX + LTZ);

  float sc[Cin], sh[Cin];
#pragma unroll
  for (int ci = 0; ci < Cin; ci++) {
    sc[ci] = ssin[2 * ci];
    sh[ci] = ssin[2 * ci + 1];
  }

  int ox = 2 * tx0 - 1, oy = 2 * ty0 - 1, oz = 2 * tz0 - 1;
  for (int i = tid; i < NS; i += NT) {
    int sz = i / 289;
    int r = i - sz * 289;
    int sy = r / 17;
    int sxx = r - sy * 17;
    int gz = oz + sz, gy = oy + sy, gx = ox + sxx;
    float v[Cin];
#pragma unroll
    for (int ci = 0; ci < Cin; ci++) v[ci] = 0.f;
    if ((unsigned)gz < (unsigned)Din && (unsigned)gy < (unsigned)Din &&
        (unsigned)gx < (unsigned)Din) {
      int gi = ((b * Din + gz) * Din + gy) * Din + gx;
      if (mi[gi]) {
        const Tin* yp = yin + (size_t)gi * Cin;
#pragma unroll
        for (int ci = 0; ci < Cin; ci++)
          v[ci] = fmaxf(fmaf(ldy(yp, ci), sc[ci], sh[ci]), 0.f);
      }
    }
#pragma unroll
    for (int ci = 0; ci < Cin; ci++) sx[i * Cin + ci] = v[ci];
  }
  __syncthreads();

  int lx = tid & 7, ly = (tid >> 3) & 7, lz = tid >> 6;  // lz in [0,TZ)
  int vo = ((b * Dout + tz0 + lz) * Dout + ty0 + ly) * Dout + tx0 + lx;
  bool act = mo[vo] != 0;
  float acc[Cout];
#pragma unroll
  for (int co = 0; co < Cout; co++) acc[co] = 0.f;
  if (act) {
    int base = ((2 * lz) * 289 + (2 * ly) * 17 + (2 * lx)) * Cin;
#pragma unroll
    for (int dz = 0; dz < 3; dz++)
#pragma unroll
      for (int dy = 0; dy < 3; dy++)
#pragma unroll
        for (int dx = 0; dx < 3; dx++) {
          int off = base + (dz * 289 + dy * 17 + dx) * Cin;
          const float* wp = w + ((dz * 3 + dy) * 3 + dx) * Cin * Cout;
#pragma unroll
          for (int ci = 0; ci < Cin; ci++) {
            float s = sx[off + ci];
#pragma unroll
            for (int co = 0; co < Cout; co++)
              acc[co] = fmaf(s, wp[ci * Cout + co], acc[co]);
          }
        }
  }
  // store
  if constexpr (sizeof(Tout) == 2) {
#pragma unroll
    for (int k = 0; k < Cout / 2; k++) {
      __hip_bfloat162 pk;
      pk.x = __float2bfloat16(acc[2 * k]);
      pk.y = __float2bfloat16(acc[2 * k + 1]);
      ((__hip_bfloat162*)yout)[(size_t)vo * (Cout / 2) + k] = pk;
    }
  } else {
#pragma unroll
    for (int co = 0; co < Cout; co++) sty(yout, (size_t)vo * Cout + co, acc[co]);
  }
  // stats (deterministic)
  unsigned long long bal = __ballot(act);
  int wave = tid >> 6, lane = tid & 63;
#pragma unroll
  for (int co = 0; co < Cout; co++) {
    float s = acc[co], q = acc[co] * acc[co];
#pragma unroll
    for (int off = 32; off >= 1; off >>= 1) {
      s += __shfl_xor(s, off);
      q += __shfl_xor(q, off);
    }
    if (lane == 0) {
      sm[wave][2 * co] = s;
      sm[wave][2 * co + 1] = q;
    }
  }
  if (lane == 0) sm[wave][2 * Cout] = (float)__popcll(bal);
  __syncthreads();
  if (tid < REC) {
    float t = 0.f;
#pragma unroll
    for (int wv = 0; wv < TZ; wv++) t += sm[wv][tid];
    partials[(size_t)blk * REC + tid] = t;
  }
}

// ---------------- generic stride-2 conv (small layers), BN+ReLU folded ----------------
template <int Din, int Cin, int Cout, typename Tin, typename Tout>
__global__ __launch_bounds__(256) void conv_s2_k(const Tin* __restrict__ yin,
                                                 const uint8_t* __restrict__ mi,
                                                 const uint8_t* __restrict__ mo,
                                                 const float* __restrict__ ssin,  // [2*Cin]
                                                 const float* __restrict__ w,     // [27][Cin][Cout]
                                                 Tout* __restrict__ yout,
                                                 float* __restrict__ partials) {
  constexpr int Dout = Din / 2;
  constexpr int LD = il2(Dout);
  constexpr int LC = il2(Cout);
  constexpr int REC = 2 * Cout + 1;
  int tid = threadIdx.x;
  int lin = blockIdx.x * 256 + tid;
  int co = lin & (Cout - 1);
  int v = lin >> LC;
  int x = v & (Dout - 1);
  int y = (v >> LD) & (Dout - 1);
  int z = (v >> (2 * LD)) & (Dout - 1);
  int b = v >> (3 * LD);
  bool act = mo[v] != 0;
  float acc = 0.f;
  if (act) {
    for (int dz = 0; dz < 3; dz++) {
      int iz = 2 * z + dz - 1;
      if ((unsigned)iz >= (unsigned)Din) continue;
      for (int dy = 0; dy < 3; dy++) {
        int iy = 2 * y + dy - 1;
        if ((unsigned)iy >= (unsigned)Din) continue;
        for (int dx = 0; dx < 3; dx++) {
          int ix = 2 * x + dx - 1;
          if ((unsigned)ix >= (unsigned)Din) continue;
          int gi = ((b * Din + iz) * Din + iy) * Din + ix;
          if (mi[gi]) {
            const Tin* yp = yin + (size_t)gi * Cin;
            const float* wp = w + ((dz * 3 + dy) * 3 + dx) * Cin * Cout + co;
#pragma unroll
            for (int ci = 0; ci < Cin; ci++) {
              float val = fmaxf(fmaf(ldy(yp, ci), ssin[2 * ci], ssin[2 * ci + 1]), 0.f);
              acc = fmaf(val, wp[ci * Cout], acc);
            }
          }
        }
      }
    }
  }
  sty(yout, (size_t)lin, acc);
  float s = acc, q = acc * acc;
#pragma unroll
  for (int off = 32; off >= Cout; off >>= 1) {
    s += __shfl_xor(s, off);
    q += __shfl_xor(q, off);
  }
  unsigned long long bal = __ballot(act && co == 0);
  __shared__ float sm[4][REC];
  int wave = tid >> 6, lane = tid & 63;
  if (lane < Cout) {
    sm[wave][2 * lane] = s;
    sm[wave][2 * lane + 1] = q;
  }
  if (lane == 0) sm[wave][2 * Cout] = (float)__popcll(bal);
  __syncthreads();
  if (tid < REC)
    partials[(size_t)blockIdx.x * REC + tid] = sm[0][tid] + sm[1][tid] + sm[2][tid] + sm[3][tid];
}

// ---------------- stat reduce: partials -> per-channel (scale, shift) ----------------
template <int Cout>
__global__ __launch_bounds__(256) void stats_k(const float* __restrict__ partials, int nblocks,
                                               const float* __restrict__ g,
                                               const float* __restrict__ bb,
                                               float* __restrict__ ss) {
  constexpr int REC = 2 * Cout + 1;
  int c = blockIdx.x, tid = threadIdx.x;
  float s = 0.f, q = 0.f, n = 0.f;
  for (int i = tid; i < nblocks; i += 256) {
    const float* p = partials + (size_t)i * REC;
    s += p[2 * c];
    q += p[2 * c + 1];
    n += p[2 * Cout];
  }
  __shared__ float S[256], Q[256], N[256];
  S[tid] = s;
  Q[tid] = q;
  N[tid] = n;
  __syncthreads();
  for (int st = 128; st > 0; st >>= 1) {
    if (tid < st) {
      S[tid] += S[tid + st];
      Q[tid] += Q[tid + st];
      N[tid] += N[tid + st];
    }
    __syncthreads();
  }
  if (tid == 0) {
    float cnt = fmaxf(N[0], 1.f);
    float mean = S[0] / cnt;
    float var = Q[0] / cnt - mean * mean;
    float scale = g[c] * rsqrtf(var + 1e-5f);
    ss[2 * c] = scale;
    ss[2 * c + 1] = bb[c] - mean * scale;
  }
}

// ---------------- final sparse max pool 3x3x3 s2 pad1: 4^3 -> 2^3 ----------------
__global__ __launch_bounds__(512) void pool_k(const float* __restrict__ y5,
                                              const uint8_t* __restrict__ m5,
                                              const uint8_t* __restrict__ m6,
                                              const float* __restrict__ ss,
                                              float* __restrict__ out) {
  int b = blockIdx.x, tid = threadIdx.x;
  int c = tid & 63, s = tid >> 6;
  int qx = s & 1, qy = (s >> 1) & 1, qz = (s >> 2) & 1;
  int ov = ((b * 2 + qz) * 2 + qy) * 2 + qx;
  float scale = ss[2 * c], shift = ss[2 * c + 1];
  float mx = 0.f;
  for (int dz = 0; dz < 3; dz++) {
    int iz = 2 * qz + dz - 1;
    if ((unsigned)iz >= 4u) continue;
    for (int dy = 0; dy < 3; dy++) {
      int iy = 2 * qy + dy - 1;
      if ((unsigned)iy >= 4u) continue;
      for (int dx = 0; dx < 3; dx++) {
        int ix = 2 * qx + dx - 1;
        if ((unsigned)ix >= 4u) continue;
        int gi = ((b * 4 + iz) * 4 + iy) * 4 + ix;
        if (m5[gi]) {
          float val = fmaxf(fmaf(y5[gi * 64 + c], scale, shift), 0.f);
          mx = fmaxf(mx, val);
        }
      }
    }
  }
  out[ov * 64 + c] = m6[ov] ? mx : 0.f;
}

extern "C" void kernel_launch(void* const* d_in, const int* in_sizes, int n_in,
                              void* d_out, int out_size, void* d_ws, size_t ws_size,
                              hipStream_t stream) {
  const float* x = (const float*)d_in[0];
  const int* msk = (const int*)d_in[1];
  const float *w[6], *g[6], *bb[6];
  for (int i = 0; i < 6; i++) {
    w[i] = (const float*)d_in[2 + 3 * i];
    g[i] = (const float*)d_in[3 + 3 * i];
    bb[i] = (const float*)d_in[4 + 3 * i];
  }

  char* ws = (char*)d_ws;
  size_t o = 0;
  auto A = [&](size_t bytes) -> char* {
    char* p = ws + o;
    o = (o + bytes + 255) & ~(size_t)255;
    return p;
  };
  __hip_bfloat16* y0 = (__hip_bfloat16*)A(33554432 * 2);  // 64 MB
  __hip_bfloat16* y1 = (__hip_bfloat16*)A(8388608 * 2);   // 16 MB
  float* y2 = (float*)A(8388608);
  float* y3 = (float*)A(2097152);
  float* y4 = (float*)A(524288);
  float* y5 = (float*)A(131072);
  uint8_t* m0 = (uint8_t*)A(16777216);
  uint8_t* m1 = (uint8_t*)A(2097152);
  uint8_t* m2 = (uint8_t*)A(262144);
  uint8_t* m3 = (uint8_t*)A(32768);
  uint8_t* m4 = (uint8_t*)A(4096);
  uint8_t* m5 = (uint8_t*)A(512);
  uint8_t* m6 = (uint8_t*)A(64);
  float* part = (float*)A(2 << 20);
  float* ss = (float*)A(4096);
  if (o > ws_size) return;  // cannot run safely

  mask_prep_k<<<16384, 256, 0, stream>>>(msk, m0);
  down_mask_k<64><<<8192, 256, 0, stream>>>(m0, m1);
  down_mask_k<32><<<1024, 256, 0, stream>>>(m1, m2);
  down_mask_k<16><<<128, 256, 0, stream>>>(m2, m3);
  down_mask_k<8><<<16, 256, 0, stream>>>(m3, m4);
  down_mask_k<4><<<2, 256, 0, stream>>>(m4, m5);
  down_mask_k<2><<<1, 256, 0, stream>>>(m5, m6);

  conv0_k<<<32768, 512, 0, stream>>>(x, m0, w[0], y0, part);
  stats_k<2><<<2, 256, 0, stream>>>(part, 32768, g[0], bb[0], ss + 0);
  // layer 1: 128 -> 64, Cin=2, Cout=4, LDS-tiled (8x8x8 out tile, 512 thr)
  conv_tile_k<128, 2, 4, 8, __hip_bfloat16, __hip_bfloat16>
      <<<4096, 512, 0, stream>>>(y0, m0, m1, ss + 0, w[1], y1, part);
  stats_k<4><<<4, 256, 0, stream>>>(part, 4096, g[1], bb[1], ss + 128);
  // layer 2: 64 -> 32, Cin=4, Cout=8, LDS-tiled (8x8x4 out tile, 256 thr)
  conv_tile_k<64, 4, 8, 4, __hip_bfloat16, float>
      <<<1024, 256, 0, stream>>>(y1, m1, m2, ss + 128, w[2], y2, part);
  stats_k<8><<<8, 256, 0, stream>>>(part, 1024, g[2], bb[2], ss + 256);
  conv_s2_k<32, 8, 16, float, float>
      <<<2048, 256, 0, stream>>>(y2, m2, m3, ss + 256, w[3], y3, part);
  stats_k<16><<<16, 256, 0, stream>>>(part, 2048, g[3], bb[3], ss + 384);
  conv_s2_k<16, 16, 32, float, float>
      <<<512, 256, 0, stream>>>(y3, m3, m4, ss + 384, w[4], y4, part);
  stats_k<32><<<32, 256, 0, stream>>>(part, 512, g[4], bb[4], ss + 512);
  conv_s2_k<8, 32, 64, float, float>
      <<<128, 256, 0, stream>>>(y4, m4, m5, ss + 512, w[5], y5, part);
  stats_k<64><<<64, 256, 0, stream>>>(part, 128, g[5], bb[5], ss + 640);
  pool_k<<<8, 512, 0, stream>>>(y5, m5, m6, ss + 640, (float*)d_out);
}

// Round 4
// 365.607 us; speedup vs baseline: 5.1519x; 1.1587x over previous
//
#include <hip/hip_runtime.h>
#include <hip/hip_bf16.h>
#include <stdint.h>

#define DEV __device__ __forceinline__

constexpr int BATCH = 8;

constexpr int il2(int n) { return (n <= 1) ? 0 : 1 + il2(n / 2); }

DEV float ldy(const float* p, int i) { return p[i]; }
DEV float ldy(const __hip_bfloat16* p, int i) { return __bfloat162float(p[i]); }
DEV void sty(float* p, size_t i, float v) { p[i] = v; }
DEV void sty(__hip_bfloat16* p, size_t i, float v) { p[i] = __float2bfloat16(v); }

DEV uint32_t f2bf(float v) {
  __hip_bfloat16 h = __float2bfloat16(v);
  return (uint32_t)*reinterpret_cast<uint16_t*>(&h);
}

// ---------------- maskA: int32 mask -> m0, m1, m2 (fused pyramid, LDS-tiled) ----------------
// block covers 32^3 of m0; grid = 4*4*4*8 = 512
__global__ __launch_bounds__(256) void maskA_k(const int* __restrict__ msk,
                                               uint8_t* __restrict__ m0,
                                               uint8_t* __restrict__ m1,
                                               uint8_t* __restrict__ m2) {
  __shared__ uint8_t t0[32768];
  __shared__ uint8_t t1[4096];
  int blk = blockIdx.x;
  int bx = (blk & 3) * 32, by = ((blk >> 2) & 3) * 32, bz = ((blk >> 4) & 3) * 32, b = blk >> 6;
  int tid = threadIdx.x;
  // stage 32^3 voxels as 8192 int4 groups
  for (int g = tid; g < 8192; g += 256) {
    int gx4 = (g & 7) * 4, gy = (g >> 3) & 31, gz = g >> 8;
    int gidx = ((b * 128 + bz + gz) * 128 + by + gy) * 128 + bx + gx4;
    int4 v = *(const int4*)(msk + gidx);
    uint32_t o = (v.x ? 1u : 0u) | (v.y ? 256u : 0u) | (v.z ? 65536u : 0u) | (v.w ? 16777216u : 0u);
    ((uint32_t*)t0)[g] = o;
    ((uint32_t*)m0)[gidx >> 2] = o;
  }
  __syncthreads();
  // m1: 16^3 per block
  for (int j = tid; j < 4096; j += 256) {
    int ox = j & 15, oy = (j >> 4) & 15, oz = j >> 8;
    uint32_t act = 0;
#pragma unroll
    for (int dz = 0; dz < 2; dz++)
#pragma unroll
      for (int dy = 0; dy < 2; dy++)
        act |= *(const uint16_t*)&t0[(2 * oz + dz) * 1024 + (2 * oy + dy) * 32 + 2 * ox];
    uint8_t vv = act ? 1 : 0;
    t1[j] = vv;
    m1[((b * 64 + bz / 2 + oz) * 64 + by / 2 + oy) * 64 + bx / 2 + ox] = vv;
  }
  __syncthreads();
  // m2: 8^3 per block
  for (int j = tid; j < 512; j += 256) {
    int ox = j & 7, oy = (j >> 3) & 7, oz = j >> 6;
    uint32_t act = 0;
#pragma unroll
    for (int dz = 0; dz < 2; dz++)
#pragma unroll
      for (int dy = 0; dy < 2; dy++)
        act |= *(const uint16_t*)&t1[(2 * oz + dz) * 256 + (2 * oy + dy) * 16 + 2 * ox];
    m2[((b * 32 + bz / 4 + oz) * 32 + by / 4 + oy) * 32 + bx / 4 + ox] = act ? 1 : 0;
  }
}

// ---------------- maskB: m2 -> m3, m4, m5, m6 (single block) ----------------
__global__ __launch_bounds__(1024) void maskB_k(const uint8_t* __restrict__ m2,
                                                uint8_t* __restrict__ m3,
                                                uint8_t* __restrict__ m4,
                                                uint8_t* __restrict__ m5,
                                                uint8_t* __restrict__ m6) {
  __shared__ uint8_t t3[32768];  // all of m3: 8 * 16^3
  __shared__ uint8_t t4[4096];
  __shared__ uint8_t t5[512];
  int tid = threadIdx.x;
  for (int j = tid; j < 32768; j += 1024) {
    int ox = j & 15, oy = (j >> 4) & 15, oz = (j >> 8) & 15, b = j >> 12;
    uint32_t act = 0;
#pragma unroll
    for (int dz = 0; dz < 2; dz++)
#pragma unroll
      for (int dy = 0; dy < 2; dy++)
        act |= *(const uint16_t*)&m2[((b * 32 + 2 * oz + dz) * 32 + 2 * oy + dy) * 32 + 2 * ox];
    uint8_t v = act ? 1 : 0;
    t3[j] = v;
    m3[j] = v;
  }
  __syncthreads();
  for (int j = tid; j < 4096; j += 1024) {
    int ox = j & 7, oy = (j >> 3) & 7, oz = (j >> 6) & 7, b = j >> 9;
    uint32_t act = 0;
#pragma unroll
    for (int dz = 0; dz < 2; dz++)
#pragma unroll
      for (int dy = 0; dy < 2; dy++)
        act |= *(const uint16_t*)&t3[((b * 16 + 2 * oz + dz) * 16 + 2 * oy + dy) * 16 + 2 * ox];
    uint8_t v = act ? 1 : 0;
    t4[j] = v;
    m4[j] = v;
  }
  __syncthreads();
  if (tid < 512) {
    int j = tid;
    int ox = j & 3, oy = (j >> 2) & 3, oz = (j >> 4) & 3, b = j >> 6;
    uint32_t act = 0;
#pragma unroll
    for (int dz = 0; dz < 2; dz++)
#pragma unroll
      for (int dy = 0; dy < 2; dy++)
        act |= *(const uint16_t*)&t4[((b * 8 + 2 * oz + dz) * 8 + 2 * oy + dy) * 8 + 2 * ox];
    uint8_t v = act ? 1 : 0;
    t5[j] = v;
    m5[j] = v;
  }
  __syncthreads();
  if (tid < 64) {
    int j = tid;
    int ox = j & 1, oy = (j >> 1) & 1, oz = (j >> 2) & 1, b = j >> 3;
    uint32_t act = 0;
#pragma unroll
    for (int dz = 0; dz < 2; dz++)
#pragma unroll
      for (int dy = 0; dy < 2; dy++)
        act |= *(const uint16_t*)&t5[((b * 4 + 2 * oz + dz) * 4 + 2 * oy + dy) * 4 + 2 * ox];
    m6[j] = act ? 1 : 0;
  }
}

// ---------------- layer 0 conv: Cin=1, Cout=2, stride 1, 16^3 tile, 8 voxels/thread ----------
// partials record: [s0, q0, s1, q1, active_count] per block (stride 5)
__global__ __launch_bounds__(512) void conv0_k(const float* __restrict__ x,
                                               const uint8_t* __restrict__ m0,
                                               const float* __restrict__ w,  // [27][1][2]
                                               __hip_bfloat16* __restrict__ y0,
                                               float* __restrict__ partials) {
  constexpr int RS = 20, PS = 360;
  __shared__ float sx[18 * PS];  // 6480 floats
  __shared__ float sm[8][5];
  int blk = blockIdx.x;
  int tx0 = (blk & 7) * 16, ty0 = ((blk >> 3) & 7) * 16, tz0 = ((blk >> 6) & 7) * 16, b = blk >> 9;
  int tid = threadIdx.x;
  // stage 18x18x18 halo (masked, zero-padded)
  for (int i = tid; i < 5832; i += 512) {
    int sz = i / 324;
    int r = i - sz * 324;
    int sy = r / 18;
    int sxx = r - sy * 18;
    int gz = tz0 + sz - 1, gy = ty0 + sy - 1, gx = tx0 + sxx - 1;
    float val = 0.f;
    if ((unsigned)gz < 128u && (unsigned)gy < 128u && (unsigned)gx < 128u) {
      int gi = ((b * 128 + gz) * 128 + gy) * 128 + gx;
      if (m0[gi]) val = x[gi];
    }
    sx[sz * PS + sy * RS + sxx] = val;
  }
  __syncthreads();

  int lx = (tid & 7) * 2, ly = ((tid >> 3) & 7) * 2, lz = (tid >> 6) * 2;
  // load 4x4x4 input region into registers (b64 reads, 2-way bank = free)
  float rg[4][4][4];
#pragma unroll
  for (int dz = 0; dz < 4; dz++)
#pragma unroll
    for (int dy = 0; dy < 4; dy++)
#pragma unroll
      for (int dx = 0; dx < 4; dx += 2) {
        float2 v = *(const float2*)&sx[(lz + dz) * PS + (ly + dy) * RS + lx + dx];
        rg[dz][dy][dx] = v.x;
        rg[dz][dy][dx + 1] = v.y;
      }

  float acc[2][2][2][2];  // [oz][oy][ox][ch]
#pragma unroll
  for (int oz = 0; oz < 2; oz++)
#pragma unroll
    for (int oy = 0; oy < 2; oy++)
#pragma unroll
      for (int ox = 0; ox < 2; ox++)
        acc[oz][oy][ox][0] = acc[oz][oy][ox][1] = 0.f;

#pragma unroll
  for (int dz = 0; dz < 3; dz++)
#pragma unroll
    for (int dy = 0; dy < 3; dy++)
#pragma unroll
      for (int dx = 0; dx < 3; dx++) {
        float w0 = w[((dz * 3 + dy) * 3 + dx) * 2];
        float w1 = w[((dz * 3 + dy) * 3 + dx) * 2 + 1];
#pragma unroll
        for (int oz = 0; oz < 2; oz++)
#pragma unroll
          for (int oy = 0; oy < 2; oy++)
#pragma unroll
            for (int ox = 0; ox < 2; ox++) {
              float s = rg[oz + dz][oy + dy][ox + dx];
              acc[oz][oy][ox][0] = fmaf(s, w0, acc[oz][oy][ox][0]);
              acc[oz][oy][ox][1] = fmaf(s, w1, acc[oz][oy][ox][1]);
            }
      }

  // store (unmasked; downstream gates by mask) + masked stats
  float s0 = 0.f, q0 = 0.f, s1 = 0.f, q1 = 0.f;
  int cnt = 0;
#pragma unroll
  for (int oz = 0; oz < 2; oz++)
#pragma unroll
    for (int oy = 0; oy < 2; oy++) {
      int z = tz0 + lz + oz, y = ty0 + ly + oy, xx = tx0 + lx;
      int vo = ((b * 128 + z) * 128 + y) * 128 + xx;
      uint2 st;
      st.x = f2bf(acc[oz][oy][0][0]) | (f2bf(acc[oz][oy][0][1]) << 16);
      st.y = f2bf(acc[oz][oy][1][0]) | (f2bf(acc[oz][oy][1][1]) << 16);
      ((uint2*)y0)[vo >> 1] = st;
      uint32_t mm = *(const uint16_t*)(m0 + vo);
      if (mm & 0xff) {
        s0 += acc[oz][oy][0][0];
        q0 += acc[oz][oy][0][0] * acc[oz][oy][0][0];
        s1 += acc[oz][oy][0][1];
        q1 += acc[oz][oy][0][1] * acc[oz][oy][0][1];
        cnt++;
      }
      if (mm >> 8) {
        s0 += acc[oz][oy][1][0];
        q0 += acc[oz][oy][1][0] * acc[oz][oy][1][0];
        s1 += acc[oz][oy][1][1];
        q1 += acc[oz][oy][1][1] * acc[oz][oy][1][1];
        cnt++;
      }
    }
  float cf = (float)cnt;
#pragma unroll
  for (int off = 32; off >= 1; off >>= 1) {
    s0 += __shfl_xor(s0, off);
    q0 += __shfl_xor(q0, off);
    s1 += __shfl_xor(s1, off);
    q1 += __shfl_xor(q1, off);
    cf += __shfl_xor(cf, off);
  }
  int wave = tid >> 6;
  if ((tid & 63) == 0) {
    sm[wave][0] = s0;
    sm[wave][1] = q0;
    sm[wave][2] = s1;
    sm[wave][3] = q1;
    sm[wave][4] = cf;
  }
  __syncthreads();
  if (tid < 5) {
    float t = 0.f;
#pragma unroll
    for (int wv = 0; wv < 8; wv++) t += sm[wv][tid];
    partials[blk * 5 + tid] = t;
  }
}

// ---------------- LDS-tiled stride-2 conv, BN+ReLU+mask folded at staging ----------------
template <int Din, int Cin, int Cout, int TZ, typename Tin, typename Tout>
__global__ __launch_bounds__(512) void conv_tile_k(const Tin* __restrict__ yin,
                                                   const uint8_t* __restrict__ mi,
                                                   const uint8_t* __restrict__ mo,
                                                   const float* __restrict__ ssin,  // [2*Cin]
                                                   const float* __restrict__ w,     // [27][Cin][Cout]
                                                   Tout* __restrict__ yout,
                                                   float* __restrict__ partials) {
  constexpr int Dout = Din / 2;
  constexpr int NT = 64 * TZ;
  constexpr int IZ = 2 * TZ + 1;
  constexpr int NS = 289 * IZ;
  constexpr int TXN = Dout / 8;
  constexpr int TZN = Dout / TZ;
  constexpr int LTX = il2(TXN);
  constexpr int LTZ = il2(TZN);
  constexpr int REC = 2 * Cout + 1;
  __shared__ float sx[NS * Cin];
  __shared__ float sm[TZ][REC];

  int tid = threadIdx.x;
  int blk = blockIdx.x;
  int tx0 = (blk & (TXN - 1)) * 8;
  int ty0 = ((blk >> LTX) & (TXN - 1)) * 8;
  int tz0 = ((blk >> (2 * LTX)) & (TZN - 1)) * TZ;
  int b = blk >> (2 * LTX + LTZ);

  float sc[Cin], sh[Cin];
#pragma unroll
  for (int ci = 0; ci < Cin; ci++) {
    sc[ci] = ssin[2 * ci];
    sh[ci] = ssin[2 * ci + 1];
  }

  int ox = 2 * tx0 - 1, oy = 2 * ty0 - 1, oz = 2 * tz0 - 1;
  for (int i = tid; i < NS; i += NT) {
    int sz = i / 289;
    int r = i - sz * 289;
    int sy = r / 17;
    int sxx = r - sy * 17;
    int gz = oz + sz, gy = oy + sy, gx = ox + sxx;
    float v[Cin];
#pragma unroll
    for (int ci = 0; ci < Cin; ci++) v[ci] = 0.f;
    if ((unsigned)gz < (unsigned)Din && (unsigned)gy < (unsigned)Din &&
        (unsigned)gx < (unsigned)Din) {
      int gi = ((b * Din + gz) * Din + gy) * Din + gx;
      if (mi[gi]) {
        const Tin* yp = yin + (size_t)gi * Cin;
#pragma unroll
        for (int ci = 0; ci < Cin; ci++)
          v[ci] = fmaxf(fmaf(ldy(yp, ci), sc[ci], sh[ci]), 0.f);
      }
    }
#pragma unroll
    for (int ci = 0; ci < Cin; ci++) sx[i * Cin + ci] = v[ci];
  }
  __syncthreads();

  int lx = tid & 7, ly = (tid >> 3) & 7, lz = tid >> 6;
  int vo = ((b * Dout + tz0 + lz) * Dout + ty0 + ly) * Dout + tx0 + lx;
  bool act = mo[vo] != 0;
  float acc[Cout];
#pragma unroll
  for (int co = 0; co < Cout; co++) acc[co] = 0.f;
  if (act) {
    int base = ((2 * lz) * 289 + (2 * ly) * 17 + (2 * lx)) * Cin;
#pragma unroll
    for (int dz = 0; dz < 3; dz++)
#pragma unroll
      for (int dy = 0; dy < 3; dy++)
#pragma unroll
        for (int dx = 0; dx < 3; dx++) {
          int off = base + (dz * 289 + dy * 17 + dx) * Cin;
          const float* wp = w + ((dz * 3 + dy) * 3 + dx) * Cin * Cout;
#pragma unroll
          for (int ci = 0; ci < Cin; ci++) {
            float s = sx[off + ci];
#pragma unroll
            for (int co = 0; co < Cout; co++)
              acc[co] = fmaf(s, wp[ci * Cout + co], acc[co]);
          }
        }
  }
  if constexpr (sizeof(Tout) == 2) {
#pragma unroll
    for (int k = 0; k < Cout / 2; k++) {
      __hip_bfloat162 pk;
      pk.x = __float2bfloat16(acc[2 * k]);
      pk.y = __float2bfloat16(acc[2 * k + 1]);
      ((__hip_bfloat162*)yout)[(size_t)vo * (Cout / 2) + k] = pk;
    }
  } else {
#pragma unroll
    for (int co = 0; co < Cout; co++) sty(yout, (size_t)vo * Cout + co, acc[co]);
  }
  unsigned long long bal = __ballot(act);
  int wave = tid >> 6, lane = tid & 63;
#pragma unroll
  for (int co = 0; co < Cout; co++) {
    float s = acc[co], q = acc[co] * acc[co];
#pragma unroll
    for (int off = 32; off >= 1; off >>= 1) {
      s += __shfl_xor(s, off);
      q += __shfl_xor(q, off);
    }
    if (lane == 0) {
      sm[wave][2 * co] = s;
      sm[wave][2 * co + 1] = q;
    }
  }
  if (lane == 0) sm[wave][2 * Cout] = (float)__popcll(bal);
  __syncthreads();
  if (tid < REC) {
    float t = 0.f;
#pragma unroll
    for (int wv = 0; wv < TZ; wv++) t += sm[wv][tid];
    partials[(size_t)blk * REC + tid] = t;
  }
}

// ---------------- generic stride-2 conv (small layers), BN+ReLU folded ----------------
template <int Din, int Cin, int Cout, typename Tin, typename Tout>
__global__ __launch_bounds__(256) void conv_s2_k(const Tin* __restrict__ yin,
                                                 const uint8_t* __restrict__ mi,
                                                 const uint8_t* __restrict__ mo,
                                                 const float* __restrict__ ssin,
                                                 const float* __restrict__ w,
                                                 Tout* __restrict__ yout,
                                                 float* __restrict__ partials) {
  constexpr int Dout = Din / 2;
  constexpr int LD = il2(Dout);
  constexpr int LC = il2(Cout);
  constexpr int REC = 2 * Cout + 1;
  int tid = threadIdx.x;
  int lin = blockIdx.x * 256 + tid;
  int co = lin & (Cout - 1);
  int v = lin >> LC;
  int x = v & (Dout - 1);
  int y = (v >> LD) & (Dout - 1);
  int z = (v >> (2 * LD)) & (Dout - 1);
  int b = v >> (3 * LD);
  bool act = mo[v] != 0;
  float acc = 0.f;
  if (act) {
    for (int dz = 0; dz < 3; dz++) {
      int iz = 2 * z + dz - 1;
      if ((unsigned)iz >= (unsigned)Din) continue;
      for (int dy = 0; dy < 3; dy++) {
        int iy = 2 * y + dy - 1;
        if ((unsigned)iy >= (unsigned)Din) continue;
        for (int dx = 0; dx < 3; dx++) {
          int ix = 2 * x + dx - 1;
          if ((unsigned)ix >= (unsigned)Din) continue;
          int gi = ((b * Din + iz) * Din + iy) * Din + ix;
          if (mi[gi]) {
            const Tin* yp = yin + (size_t)gi * Cin;
            const float* wp = w + ((dz * 3 + dy) * 3 + dx) * Cin * Cout + co;
#pragma unroll
            for (int ci = 0; ci < Cin; ci++) {
              float val = fmaxf(fmaf(ldy(yp, ci), ssin[2 * ci], ssin[2 * ci + 1]), 0.f);
              acc = fmaf(val, wp[ci * Cout], acc);
            }
          }
        }
      }
    }
  }
  sty(yout, (size_t)lin, acc);
  float s = acc, q = acc * acc;
#pragma unroll
  for (int off = 32; off >= Cout; off >>= 1) {
    s += __shfl_xor(s, off);
    q += __shfl_xor(q, off);
  }
  unsigned long long bal = __ballot(act && co == 0);
  __shared__ float sm[4][REC];
  int wave = tid >> 6, lane = tid & 63;
  if (lane < Cout) {
    sm[wave][2 * lane] = s;
    sm[wave][2 * lane + 1] = q;
  }
  if (lane == 0) sm[wave][2 * Cout] = (float)__popcll(bal);
  __syncthreads();
  if (tid < REC)
    partials[(size_t)blockIdx.x * REC + tid] = sm[0][tid] + sm[1][tid] + sm[2][tid] + sm[3][tid];
}

// ---------------- stat reduce: partials -> per-channel (scale, shift) ----------------
template <int Cout>
__global__ __launch_bounds__(256) void stats_k(const float* __restrict__ partials, int nblocks,
                                               const float* __restrict__ g,
                                               const float* __restrict__ bb,
                                               float* __restrict__ ss) {
  constexpr int REC = 2 * Cout + 1;
  int c = blockIdx.x, tid = threadIdx.x;
  float s = 0.f, q = 0.f, n = 0.f;
  for (int i = tid; i < nblocks; i += 256) {
    const float* p = partials + (size_t)i * REC;
    s += p[2 * c];
    q += p[2 * c + 1];
    n += p[2 * Cout];
  }
  __shared__ float S[256], Q[256], N[256];
  S[tid] = s;
  Q[tid] = q;
  N[tid] = n;
  __syncthreads();
  for (int st = 128; st > 0; st >>= 1) {
    if (tid < st) {
      S[tid] += S[tid + st];
      Q[tid] += Q[tid + st];
      N[tid] += N[tid + st];
    }
    __syncthreads();
  }
  if (tid == 0) {
    float cnt = fmaxf(N[0], 1.f);
    float mean = S[0] / cnt;
    float var = Q[0] / cnt - mean * mean;
    float scale = g[c] * rsqrtf(var + 1e-5f);
    ss[2 * c] = scale;
    ss[2 * c + 1] = bb[c] - mean * scale;
  }
}

// ---------------- final: fused stats<64> + sparse max pool ----------------
__global__ __launch_bounds__(512) void pool_stats_k(const float* __restrict__ y5,
                                                    const uint8_t* __restrict__ m5,
                                                    const uint8_t* __restrict__ m6,
                                                    const float* __restrict__ partials,  // 128 x 129
                                                    const float* __restrict__ g,
                                                    const float* __restrict__ bb,
                                                    float* __restrict__ out) {
  __shared__ float ssc[64], ssh[64];
  int b = blockIdx.x, tid = threadIdx.x;
  if (tid < 64) {
    float s = 0.f, q = 0.f, n = 0.f;
    for (int i = 0; i < 128; i++) {
      const float* p = partials + i * 129;
      s += p[2 * tid];
      q += p[2 * tid + 1];
      n += p[128];
    }
    float cnt = fmaxf(n, 1.f);
    float mean = s / cnt;
    float var = q / cnt - mean * mean;
    float scale = g[tid] * rsqrtf(var + 1e-5f);
    ssc[tid] = scale;
    ssh[tid] = bb[tid] - mean * scale;
  }
  __syncthreads();
  int c = tid & 63, s = tid >> 6;
  int qx = s & 1, qy = (s >> 1) & 1, qz = (s >> 2) & 1;
  int ov = ((b * 2 + qz) * 2 + qy) * 2 + qx;
  float scale = ssc[c], shift = ssh[c];
  float mx = 0.f;
  for (int dz = 0; dz < 3; dz++) {
    int iz = 2 * qz + dz - 1;
    if ((unsigned)iz >= 4u) continue;
    for (int dy = 0; dy < 3; dy++) {
      int iy = 2 * qy + dy - 1;
      if ((unsigned)iy >= 4u) continue;
      for (int dx = 0; dx < 3; dx++) {
        int ix = 2 * qx + dx - 1;
        if ((unsigned)ix >= 4u) continue;
        int gi = ((b * 4 + iz) * 4 + iy) * 4 + ix;
        if (m5[gi]) {
          float val = fmaxf(fmaf(y5[gi * 64 + c], scale, shift), 0.f);
          mx = fmaxf(mx, val);
        }
      }
    }
  }
  out[ov * 64 + c] = m6[ov] ? mx : 0.f;
}

extern "C" void kernel_launch(void* const* d_in, const int* in_sizes, int n_in,
                              void* d_out, int out_size, void* d_ws, size_t ws_size,
                              hipStream_t stream) {
  const float* x = (const float*)d_in[0];
  const int* msk = (const int*)d_in[1];
  const float *w[6], *g[6], *bb[6];
  for (int i = 0; i < 6; i++) {
    w[i] = (const float*)d_in[2 + 3 * i];
    g[i] = (const float*)d_in[3 + 3 * i];
    bb[i] = (const float*)d_in[4 + 3 * i];
  }

  char* ws = (char*)d_ws;
  size_t o = 0;
  auto A = [&](size_t bytes) -> char* {
    char* p = ws + o;
    o = (o + bytes + 255) & ~(size_t)255;
    return p;
  };
  __hip_bfloat16* y0 = (__hip_bfloat16*)A(33554432 * 2);  // 64 MB
  __hip_bfloat16* y1 = (__hip_bfloat16*)A(8388608 * 2);   // 16 MB
  float* y2 = (float*)A(8388608);
  float* y3 = (float*)A(2097152);
  float* y4 = (float*)A(524288);
  float* y5 = (float*)A(131072);
  uint8_t* m0 = (uint8_t*)A(16777216);
  uint8_t* m1 = (uint8_t*)A(2097152);
  uint8_t* m2 = (uint8_t*)A(262144);
  uint8_t* m3 = (uint8_t*)A(32768);
  uint8_t* m4 = (uint8_t*)A(4096);
  uint8_t* m5 = (uint8_t*)A(512);
  uint8_t* m6 = (uint8_t*)A(64);
  float* part = (float*)A(2 << 20);
  float* ss = (float*)A(4096);
  if (o > ws_size) return;  // cannot run safely

  maskA_k<<<512, 256, 0, stream>>>(msk, m0, m1, m2);
  maskB_k<<<1, 1024, 0, stream>>>(m2, m3, m4, m5, m6);

  conv0_k<<<4096, 512, 0, stream>>>(x, m0, w[0], y0, part);
  stats_k<2><<<2, 256, 0, stream>>>(part, 4096, g[0], bb[0], ss + 0);
  conv_tile_k<128, 2, 4, 8, __hip_bfloat16, __hip_bfloat16>
      <<<4096, 512, 0, stream>>>(y0, m0, m1, ss + 0, w[1], y1, part);
  stats_k<4><<<4, 256, 0, stream>>>(part, 4096, g[1], bb[1], ss + 128);
  conv_tile_k<64, 4, 8, 4, __hip_bfloat16, float>
      <<<1024, 256, 0, stream>>>(y1, m1, m2, ss + 128, w[2], y2, part);
  stats_k<8><<<8, 256, 0, stream>>>(part, 1024, g[2], bb[2], ss + 256);
  conv_s2_k<32, 8, 16, float, float>
      <<<2048, 256, 0, stream>>>(y2, m2, m3, ss + 256, w[3], y3, part);
  stats_k<16><<<16, 256, 0, stream>>>(part, 2048, g[3], bb[3], ss + 384);
  conv_s2_k<16, 16, 32, float, float>
      <<<512, 256, 0, stream>>>(y3, m3, m4, ss + 384, w[4], y4, part);
  stats_k<32><<<32, 256, 0, stream>>>(part, 512, g[4], bb[4], ss + 512);
  conv_s2_k<8, 32, 64, float, float>
      <<<128, 256, 0, stream>>>(y4, m4, m5, ss + 512, w[5], y5, part);
  pool_stats_k<<<8, 512, 0, stream>>>(y5, m5, m6, part, g[5], bb[5], (float*)d_out);
}

// Round 5
// 308.748 us; speedup vs baseline: 6.1007x; 1.1842x over previous
//
#include <hip/hip_runtime.h>
#include <hip/hip_bf16.h>
#include <stdint.h>

#define DEV __device__ __forceinline__

constexpr int BATCH = 8;

constexpr int il2(int n) { return (n <= 1) ? 0 : 1 + il2(n / 2); }

DEV float ldy(const float* p, int i) { return p[i]; }
DEV float ldy(const __hip_bfloat16* p, int i) { return __bfloat162float(p[i]); }
DEV void sty(float* p, size_t i, float v) { p[i] = v; }
DEV void sty(__hip_bfloat16* p, size_t i, float v) { p[i] = __float2bfloat16(v); }

DEV uint32_t f2bf(float v) {
  __hip_bfloat16 h = __float2bfloat16(v);
  return (uint32_t)*reinterpret_cast<uint16_t*>(&h);
}
DEV float bfraw(uint32_t u) {
  uint32_t t = u << 16;
  float f;
  __builtin_memcpy(&f, &t, 4);
  return f;
}
// XCD-aware swizzle (bijective when nwg % 8 == 0): contiguous tile chunks per XCD
DEV int xswz(int o, int nwg) { return (o & 7) * (nwg >> 3) + (o >> 3); }

// ---------------- maskA: int32 mask -> m0, m1, m2 (fused pyramid, LDS-tiled) ----------------
__global__ __launch_bounds__(256) void maskA_k(const int* __restrict__ msk,
                                               uint8_t* __restrict__ m0,
                                               uint8_t* __restrict__ m1,
                                               uint8_t* __restrict__ m2) {
  __shared__ uint8_t t0[32768];
  __shared__ uint8_t t1[4096];
  int blk = blockIdx.x;
  int bx = (blk & 3) * 32, by = ((blk >> 2) & 3) * 32, bz = ((blk >> 4) & 3) * 32, b = blk >> 6;
  int tid = threadIdx.x;
  for (int g = tid; g < 8192; g += 256) {
    int gx4 = (g & 7) * 4, gy = (g >> 3) & 31, gz = g >> 8;
    int gidx = ((b * 128 + bz + gz) * 128 + by + gy) * 128 + bx + gx4;
    int4 v = *(const int4*)(msk + gidx);
    uint32_t o = (v.x ? 1u : 0u) | (v.y ? 256u : 0u) | (v.z ? 65536u : 0u) | (v.w ? 16777216u : 0u);
    ((uint32_t*)t0)[g] = o;
    ((uint32_t*)m0)[gidx >> 2] = o;
  }
  __syncthreads();
  for (int j = tid; j < 4096; j += 256) {
    int ox = j & 15, oy = (j >> 4) & 15, oz = j >> 8;
    uint32_t act = 0;
#pragma unroll
    for (int dz = 0; dz < 2; dz++)
#pragma unroll
      for (int dy = 0; dy < 2; dy++)
        act |= *(const uint16_t*)&t0[(2 * oz + dz) * 1024 + (2 * oy + dy) * 32 + 2 * ox];
    uint8_t vv = act ? 1 : 0;
    t1[j] = vv;
    m1[((b * 64 + bz / 2 + oz) * 64 + by / 2 + oy) * 64 + bx / 2 + ox] = vv;
  }
  __syncthreads();
  for (int j = tid; j < 512; j += 256) {
    int ox = j & 7, oy = (j >> 3) & 7, oz = j >> 6;
    uint32_t act = 0;
#pragma unroll
    for (int dz = 0; dz < 2; dz++)
#pragma unroll
      for (int dy = 0; dy < 2; dy++)
        act |= *(const uint16_t*)&t1[(2 * oz + dz) * 256 + (2 * oy + dy) * 16 + 2 * ox];
    m2[((b * 32 + bz / 4 + oz) * 32 + by / 4 + oy) * 32 + bx / 4 + ox] = act ? 1 : 0;
  }
}

// ---------------- maskB: m2 -> m3, m4, m5, m6 (single block) ----------------
__global__ __launch_bounds__(1024) void maskB_k(const uint8_t* __restrict__ m2,
                                                uint8_t* __restrict__ m3,
                                                uint8_t* __restrict__ m4,
                                                uint8_t* __restrict__ m5,
                                                uint8_t* __restrict__ m6) {
  __shared__ uint8_t t3[32768];
  __shared__ uint8_t t4[4096];
  __shared__ uint8_t t5[512];
  int tid = threadIdx.x;
  for (int j = tid; j < 32768; j += 1024) {
    int ox = j & 15, oy = (j >> 4) & 15, oz = (j >> 8) & 15, b = j >> 12;
    uint32_t act = 0;
#pragma unroll
    for (int dz = 0; dz < 2; dz++)
#pragma unroll
      for (int dy = 0; dy < 2; dy++)
        act |= *(const uint16_t*)&m2[((b * 32 + 2 * oz + dz) * 32 + 2 * oy + dy) * 32 + 2 * ox];
    uint8_t v = act ? 1 : 0;
    t3[j] = v;
    m3[j] = v;
  }
  __syncthreads();
  for (int j = tid; j < 4096; j += 1024) {
    int ox = j & 7, oy = (j >> 3) & 7, oz = (j >> 6) & 7, b = j >> 9;
    uint32_t act = 0;
#pragma unroll
    for (int dz = 0; dz < 2; dz++)
#pragma unroll
      for (int dy = 0; dy < 2; dy++)
        act |= *(const uint16_t*)&t3[((b * 16 + 2 * oz + dz) * 16 + 2 * oy + dy) * 16 + 2 * ox];
    uint8_t v = act ? 1 : 0;
    t4[j] = v;
    m4[j] = v;
  }
  __syncthreads();
  if (tid < 512) {
    int j = tid;
    int ox = j & 3, oy = (j >> 2) & 3, oz = (j >> 4) & 3, b = j >> 6;
    uint32_t act = 0;
#pragma unroll
    for (int dz = 0; dz < 2; dz++)
#pragma unroll
      for (int dy = 0; dy < 2; dy++)
        act |= *(const uint16_t*)&t4[((b * 8 + 2 * oz + dz) * 8 + 2 * oy + dy) * 8 + 2 * ox];
    uint8_t v = act ? 1 : 0;
    t5[j] = v;
    m5[j] = v;
  }
  __syncthreads();
  if (tid < 64) {
    int j = tid;
    int ox = j & 1, oy = (j >> 1) & 1, oz = (j >> 2) & 1, b = j >> 3;
    uint32_t act = 0;
#pragma unroll
    for (int dz = 0; dz < 2; dz++)
#pragma unroll
      for (int dy = 0; dy < 2; dy++)
        act |= *(const uint16_t*)&t5[((b * 4 + 2 * oz + dz) * 4 + 2 * oy + dy) * 4 + 2 * ox];
    m6[j] = act ? 1 : 0;
  }
}

// ---------------- layer 0 conv: Cin=1, Cout=2, stride 1, 16^3 tile, 8 voxels/thread ----------
__global__ __launch_bounds__(512) void conv0_k(const float* __restrict__ x,
                                               const uint8_t* __restrict__ m0,
                                               const float* __restrict__ w,  // [27][1][2]
                                               __hip_bfloat16* __restrict__ y0,
                                               float* __restrict__ partials) {
  constexpr int RS = 20, PS = 360;
  __shared__ float sx[18 * PS];
  __shared__ uint8_t smask[4096];
  __shared__ float sm[8][5];
  int blk = xswz(blockIdx.x, 4096);
  int tx0 = (blk & 7) * 16, ty0 = ((blk >> 3) & 7) * 16, tz0 = ((blk >> 6) & 7) * 16, b = blk >> 9;
  int tid = threadIdx.x;
  // stage 18x18x18 halo (masked, zero-padded); independent mask/x loads + select
  for (int i = tid; i < 5832; i += 512) {
    int sz = i / 324;
    int r = i - sz * 324;
    int sy = r / 18;
    int sxx = r - sy * 18;
    int gz = tz0 + sz - 1, gy = ty0 + sy - 1, gx = tx0 + sxx - 1;
    float val = 0.f;
    uint8_t mb = 0;
    if ((unsigned)gz < 128u && (unsigned)gy < 128u && (unsigned)gx < 128u) {
      int gi = ((b * 128 + gz) * 128 + gy) * 128 + gx;
      mb = m0[gi];
      float xv = x[gi];
      val = mb ? xv : 0.f;
    }
    sx[sz * PS + sy * RS + sxx] = val;
    unsigned inz = (unsigned)(sz - 1), iny = (unsigned)(sy - 1), inx = (unsigned)(sxx - 1);
    if (inz < 16u && iny < 16u && inx < 16u) smask[(inz * 16 + iny) * 16 + inx] = mb;
  }
  __syncthreads();

  int lx = (tid & 7) * 2, ly = ((tid >> 3) & 7) * 2, lz = (tid >> 6) * 2;
  float rg[4][4][4];
#pragma unroll
  for (int dz = 0; dz < 4; dz++)
#pragma unroll
    for (int dy = 0; dy < 4; dy++)
#pragma unroll
      for (int dx = 0; dx < 4; dx += 2) {
        float2 v = *(const float2*)&sx[(lz + dz) * PS + (ly + dy) * RS + lx + dx];
        rg[dz][dy][dx] = v.x;
        rg[dz][dy][dx + 1] = v.y;
      }

  float acc[2][2][2][2];  // [oz][oy][ox][ch]
#pragma unroll
  for (int oz = 0; oz < 2; oz++)
#pragma unroll
    for (int oy = 0; oy < 2; oy++)
#pragma unroll
      for (int ox = 0; ox < 2; ox++)
        acc[oz][oy][ox][0] = acc[oz][oy][ox][1] = 0.f;

#pragma unroll
  for (int dz = 0; dz < 3; dz++)
#pragma unroll
    for (int dy = 0; dy < 3; dy++)
#pragma unroll
      for (int dx = 0; dx < 3; dx++) {
        float w0 = w[((dz * 3 + dy) * 3 + dx) * 2];
        float w1 = w[((dz * 3 + dy) * 3 + dx) * 2 + 1];
#pragma unroll
        for (int oz = 0; oz < 2; oz++)
#pragma unroll
          for (int oy = 0; oy < 2; oy++)
#pragma unroll
            for (int ox = 0; ox < 2; ox++) {
              float s = rg[oz + dz][oy + dy][ox + dx];
              acc[oz][oy][ox][0] = fmaf(s, w0, acc[oz][oy][ox][0]);
              acc[oz][oy][ox][1] = fmaf(s, w1, acc[oz][oy][ox][1]);
            }
      }

  // store (unmasked; downstream gates by mask) + masked stats from LDS mask
  float s0 = 0.f, q0 = 0.f, s1 = 0.f, q1 = 0.f;
  int cnt = 0;
#pragma unroll
  for (int oz = 0; oz < 2; oz++)
#pragma unroll
    for (int oy = 0; oy < 2; oy++) {
      int z = tz0 + lz + oz, y = ty0 + ly + oy, xx = tx0 + lx;
      int vo = ((b * 128 + z) * 128 + y) * 128 + xx;
      uint2 st;
      st.x = f2bf(acc[oz][oy][0][0]) | (f2bf(acc[oz][oy][0][1]) << 16);
      st.y = f2bf(acc[oz][oy][1][0]) | (f2bf(acc[oz][oy][1][1]) << 16);
      ((uint2*)y0)[vo >> 1] = st;
      uint32_t mm = *(const uint16_t*)&smask[((lz + oz) * 16 + ly + oy) * 16 + lx];
      if (mm & 0xff) {
        s0 += acc[oz][oy][0][0];
        q0 += acc[oz][oy][0][0] * acc[oz][oy][0][0];
        s1 += acc[oz][oy][0][1];
        q1 += acc[oz][oy][0][1] * acc[oz][oy][0][1];
        cnt++;
      }
      if (mm >> 8) {
        s0 += acc[oz][oy][1][0];
        q0 += acc[oz][oy][1][0] * acc[oz][oy][1][0];
        s1 += acc[oz][oy][1][1];
        q1 += acc[oz][oy][1][1] * acc[oz][oy][1][1];
        cnt++;
      }
    }
  float cf = (float)cnt;
#pragma unroll
  for (int off = 32; off >= 1; off >>= 1) {
    s0 += __shfl_xor(s0, off);
    q0 += __shfl_xor(q0, off);
    s1 += __shfl_xor(s1, off);
    q1 += __shfl_xor(q1, off);
    cf += __shfl_xor(cf, off);
  }
  int wave = tid >> 6;
  if ((tid & 63) == 0) {
    sm[wave][0] = s0;
    sm[wave][1] = q0;
    sm[wave][2] = s1;
    sm[wave][3] = q1;
    sm[wave][4] = cf;
  }
  __syncthreads();
  if (tid < 5) {
    float t = 0.f;
#pragma unroll
    for (int wv = 0; wv < 8; wv++) t += sm[wv][tid];
    partials[blk * 5 + tid] = t;
  }
}

// ---------------- LDS-tiled stride-2 conv, BN+ReLU+mask folded at staging ----------------
template <int Din, int Cin, int Cout, int TZ, typename Tin, typename Tout>
__global__ __launch_bounds__(512) void conv_tile_k(const Tin* __restrict__ yin,
                                                   const uint8_t* __restrict__ mi,
                                                   const uint8_t* __restrict__ mo,
                                                   const float* __restrict__ ssin,  // [2*Cin]
                                                   const float* __restrict__ w,     // [27][Cin][Cout]
                                                   Tout* __restrict__ yout,
                                                   float* __restrict__ partials) {
  constexpr int Dout = Din / 2;
  constexpr int NT = 64 * TZ;
  constexpr int IZ = 2 * TZ + 1;
  constexpr int NS = 289 * IZ;
  constexpr int TXN = Dout / 8;
  constexpr int TZN = Dout / TZ;
  constexpr int LTX = il2(TXN);
  constexpr int LTZ = il2(TZN);
  constexpr int NWG = TXN * TXN * TZN * BATCH;
  constexpr int REC = 2 * Cout + 1;
  __shared__ float sx[NS * Cin];
  __shared__ float sm[TZ][REC];

  int tid = threadIdx.x;
  int blk = xswz(blockIdx.x, NWG);
  int tx0 = (blk & (TXN - 1)) * 8;
  int ty0 = ((blk >> LTX) & (TXN - 1)) * 8;
  int tz0 = ((blk >> (2 * LTX)) & (TZN - 1)) * TZ;
  int b = blk >> (2 * LTX + LTZ);

  float sc[Cin], sh[Cin];
#pragma unroll
  for (int ci = 0; ci < Cin; ci++) {
    sc[ci] = ssin[2 * ci];
    sh[ci] = ssin[2 * ci + 1];
  }

  int ox = 2 * tx0 - 1, oy = 2 * ty0 - 1, oz = 2 * tz0 - 1;
  for (int i = tid; i < NS; i += NT) {
    int sz = i / 289;
    int r = i - sz * 289;
    int sy = r / 17;
    int sxx = r - sy * 17;
    int gz = oz + sz, gy = oy + sy, gx = ox + sxx;
    float v[Cin];
#pragma unroll
    for (int ci = 0; ci < Cin; ci++) v[ci] = 0.f;
    if ((unsigned)gz < (unsigned)Din && (unsigned)gy < (unsigned)Din &&
        (unsigned)gx < (unsigned)Din) {
      int gi = ((b * Din + gz) * Din + gy) * Din + gx;
      bool mm = mi[gi] != 0;
      float f[Cin];
      if constexpr (sizeof(Tin) == 2 && Cin == 2) {
        uint32_t rr = *(const uint32_t*)((const uint16_t*)yin + (size_t)gi * 2);
        f[0] = bfraw(rr & 0xffffu);
        f[1] = bfraw(rr >> 16);
      } else if constexpr (sizeof(Tin) == 2 && Cin == 4) {
        uint2 rr = *(const uint2*)((const uint16_t*)yin + (size_t)gi * 4);
        f[0] = bfraw(rr.x & 0xffffu);
        f[1] = bfraw(rr.x >> 16);
        f[2] = bfraw(rr.y & 0xffffu);
        f[3] = bfraw(rr.y >> 16);
      } else {
#pragma unroll
        for (int ci = 0; ci < Cin; ci++) f[ci] = ldy(yin + (size_t)gi * Cin, ci);
      }
#pragma unroll
      for (int ci = 0; ci < Cin; ci++)
        v[ci] = mm ? fmaxf(fmaf(f[ci], sc[ci], sh[ci]), 0.f) : 0.f;
    }
#pragma unroll
    for (int ci = 0; ci < Cin; ci++) sx[i * Cin + ci] = v[ci];
  }
  __syncthreads();

  int lx = tid & 7, ly = (tid >> 3) & 7, lz = tid >> 6;
  int vo = ((b * Dout + tz0 + lz) * Dout + ty0 + ly) * Dout + tx0 + lx;
  bool act = mo[vo] != 0;
  float acc[Cout];
#pragma unroll
  for (int co = 0; co < Cout; co++) acc[co] = 0.f;
  if (act) {
    int base = ((2 * lz) * 289 + (2 * ly) * 17 + (2 * lx)) * Cin;
#pragma unroll
    for (int dz = 0; dz < 3; dz++)
#pragma unroll
      for (int dy = 0; dy < 3; dy++)
#pragma unroll
        for (int dx = 0; dx < 3; dx++) {
          int off = base + (dz * 289 + dy * 17 + dx) * Cin;
          const float* wp = w + ((dz * 3 + dy) * 3 + dx) * Cin * Cout;
#pragma unroll
          for (int ci = 0; ci < Cin; ci++) {
            float s = sx[off + ci];
#pragma unroll
            for (int co = 0; co < Cout; co++)
              acc[co] = fmaf(s, wp[ci * Cout + co], acc[co]);
          }
        }
  }
  if constexpr (sizeof(Tout) == 2) {
    uint32_t pk[Cout / 2];
#pragma unroll
    for (int k = 0; k < Cout / 2; k++) pk[k] = f2bf(acc[2 * k]) | (f2bf(acc[2 * k + 1]) << 16);
    if constexpr (Cout == 4)
      *(uint2*)((uint16_t*)yout + (size_t)vo * 4) = *(uint2*)pk;
    else if constexpr (Cout == 8)
      *(uint4*)((uint16_t*)yout + (size_t)vo * 8) = *(uint4*)pk;
    else {
#pragma unroll
      for (int k = 0; k < Cout / 2; k++)
        *((uint32_t*)yout + (size_t)vo * (Cout / 2) + k) = pk[k];
    }
  } else {
#pragma unroll
    for (int co = 0; co < Cout; co++) sty(yout, (size_t)vo * Cout + co, acc[co]);
  }
  unsigned long long bal = __ballot(act);
  int wave = tid >> 6, lane = tid & 63;
#pragma unroll
  for (int co = 0; co < Cout; co++) {
    float s = acc[co], q = acc[co] * acc[co];
#pragma unroll
    for (int off = 32; off >= 1; off >>= 1) {
      s += __shfl_xor(s, off);
      q += __shfl_xor(q, off);
    }
    if (lane == 0) {
      sm[wave][2 * co] = s;
      sm[wave][2 * co + 1] = q;
    }
  }
  if (lane == 0) sm[wave][2 * Cout] = (float)__popcll(bal);
  __syncthreads();
  if (tid < REC) {
    float t = 0.f;
#pragma unroll
    for (int wv = 0; wv < TZ; wv++) t += sm[wv][tid];
    partials[(size_t)blk * REC + tid] = t;
  }
}

// ---------------- generic stride-2 conv (small layers), BN+ReLU folded ----------------
template <int Din, int Cin, int Cout, typename Tin, typename Tout>
__global__ __launch_bounds__(256) void conv_s2_k(const Tin* __restrict__ yin,
                                                 const uint8_t* __restrict__ mi,
                                                 const uint8_t* __restrict__ mo,
                                                 const float* __restrict__ ssin,
                                                 const float* __restrict__ w,
                                                 Tout* __restrict__ yout,
                                                 float* __restrict__ partials) {
  constexpr int Dout = Din / 2;
  constexpr int LD = il2(Dout);
  constexpr int LC = il2(Cout);
  constexpr int REC = 2 * Cout + 1;
  int tid = threadIdx.x;
  int lin = blockIdx.x * 256 + tid;
  int co = lin & (Cout - 1);
  int v = lin >> LC;
  int x = v & (Dout - 1);
  int y = (v >> LD) & (Dout - 1);
  int z = (v >> (2 * LD)) & (Dout - 1);
  int b = v >> (3 * LD);
  bool act = mo[v] != 0;
  float acc = 0.f;
  if (act) {
    for (int dz = 0; dz < 3; dz++) {
      int iz = 2 * z + dz - 1;
      if ((unsigned)iz >= (unsigned)Din) continue;
      for (int dy = 0; dy < 3; dy++) {
        int iy = 2 * y + dy - 1;
        if ((unsigned)iy >= (unsigned)Din) continue;
        for (int dx = 0; dx < 3; dx++) {
          int ix = 2 * x + dx - 1;
          if ((unsigned)ix >= (unsigned)Din) continue;
          int gi = ((b * Din + iz) * Din + iy) * Din + ix;
          if (mi[gi]) {
            const Tin* yp = yin + (size_t)gi * Cin;
            const float* wp = w + ((dz * 3 + dy) * 3 + dx) * Cin * Cout + co;
#pragma unroll
            for (int ci = 0; ci < Cin; ci++) {
              float val = fmaxf(fmaf(ldy(yp, ci), ssin[2 * ci], ssin[2 * ci + 1]), 0.f);
              acc = fmaf(val, wp[ci * Cout], acc);
            }
          }
        }
      }
    }
  }
  sty(yout, (size_t)lin, acc);
  float s = acc, q = acc * acc;
#pragma unroll
  for (int off = 32; off >= Cout; off >>= 1) {
    s += __shfl_xor(s, off);
    q += __shfl_xor(q, off);
  }
  unsigned long long bal = __ballot(act && co == 0);
  __shared__ float sm[4][REC];
  int wave = tid >> 6, lane = tid & 63;
  if (lane < Cout) {
    sm[wave][2 * lane] = s;
    sm[wave][2 * lane + 1] = q;
  }
  if (lane == 0) sm[wave][2 * Cout] = (float)__popcll(bal);
  __syncthreads();
  if (tid < REC)
    partials[(size_t)blockIdx.x * REC + tid] = sm[0][tid] + sm[1][tid] + sm[2][tid] + sm[3][tid];
}

// ---------------- stat reduce: partials -> per-channel (scale, shift) ----------------
template <int Cout>
__global__ __launch_bounds__(256) void stats_k(const float* __restrict__ partials, int nblocks,
                                               const float* __restrict__ g,
                                               const float* __restrict__ bb,
                                               float* __restrict__ ss) {
  constexpr int REC = 2 * Cout + 1;
  int c = blockIdx.x, tid = threadIdx.x;
  float s = 0.f, q = 0.f, n = 0.f;
  for (int i = tid; i < nblocks; i += 256) {
    const float* p = partials + (size_t)i * REC;
    s += p[2 * c];
    q += p[2 * c + 1];
    n += p[2 * Cout];
  }
  __shared__ float S[256], Q[256], N[256];
  S[tid] = s;
  Q[tid] = q;
  N[tid] = n;
  __syncthreads();
  for (int st = 128; st > 0; st >>= 1) {
    if (tid < st) {
      S[tid] += S[tid + st];
      Q[tid] += Q[tid + st];
      N[tid] += N[tid + st];
    }
    __syncthreads();
  }
  if (tid == 0) {
    float cnt = fmaxf(N[0], 1.f);
    float mean = S[0] / cnt;
    float var = Q[0] / cnt - mean * mean;
    float scale = g[c] * rsqrtf(var + 1e-5f);
    ss[2 * c] = scale;
    ss[2 * c + 1] = bb[c] - mean * scale;
  }
}

// ---------------- final: fused stats<64> + sparse max pool ----------------
__global__ __launch_bounds__(512) void pool_stats_k(const float* __restrict__ y5,
                                                    const uint8_t* __restrict__ m5,
                                                    const uint8_t* __restrict__ m6,
                                                    const float* __restrict__ partials,  // 128 x 129
                                                    const float* __restrict__ g,
                                                    const float* __restrict__ bb,
                                                    float* __restrict__ out) {
  __shared__ float ssc[64], ssh[64];
  int b = blockIdx.x, tid = threadIdx.x;
  if (tid < 64) {
    float s = 0.f, q = 0.f, n = 0.f;
    for (int i = 0; i < 128; i++) {
      const float* p = partials + i * 129;
      s += p[2 * tid];
      q += p[2 * tid + 1];
      n += p[128];
    }
    float cnt = fmaxf(n, 1.f);
    float mean = s / cnt;
    float var = q / cnt - mean * mean;
    float scale = g[tid] * rsqrtf(var + 1e-5f);
    ssc[tid] = scale;
    ssh[tid] = bb[tid] - mean * scale;
  }
  __syncthreads();
  int c = tid & 63, s = tid >> 6;
  int qx = s & 1, qy = (s >> 1) & 1, qz = (s >> 2) & 1;
  int ov = ((b * 2 + qz) * 2 + qy) * 2 + qx;
  float scale = ssc[c], shift = ssh[c];
  float mx = 0.f;
  for (int dz = 0; dz < 3; dz++) {
    int iz = 2 * qz + dz - 1;
    if ((unsigned)iz >= 4u) continue;
    for (int dy = 0; dy < 3; dy++) {
      int iy = 2 * qy + dy - 1;
      if ((unsigned)iy >= 4u) continue;
      for (int dx = 0; dx < 3; dx++) {
        int ix = 2 * qx + dx - 1;
        if ((unsigned)ix >= 4u) continue;
        int gi = ((b * 4 + iz) * 4 + iy) * 4 + ix;
        if (m5[gi]) {
          float val = fmaxf(fmaf(y5[gi * 64 + c], scale, shift), 0.f);
          mx = fmaxf(mx, val);
        }
      }
    }
  }
  out[ov * 64 + c] = m6[ov] ? mx : 0.f;
}

extern "C" void kernel_launch(void* const* d_in, const int* in_sizes, int n_in,
                              void* d_out, int out_size, void* d_ws, size_t ws_size,
                              hipStream_t stream) {
  const float* x = (const float*)d_in[0];
  const int* msk = (const int*)d_in[1];
  const float *w[6], *g[6], *bb[6];
  for (int i = 0; i < 6; i++) {
    w[i] = (const float*)d_in[2 + 3 * i];
    g[i] = (const float*)d_in[3 + 3 * i];
    bb[i] = (const float*)d_in[4 + 3 * i];
  }

  char* ws = (char*)d_ws;
  size_t o = 0;
  auto A = [&](size_t bytes) -> char* {
    char* p = ws + o;
    o = (o + bytes + 255) & ~(size_t)255;
    return p;
  };
  __hip_bfloat16* y0 = (__hip_bfloat16*)A(33554432 * 2);  // 64 MB
  __hip_bfloat16* y1 = (__hip_bfloat16*)A(8388608 * 2);   // 16 MB
  __hip_bfloat16* y2 = (__hip_bfloat16*)A(2097152 * 2);   // 4 MB
  float* y3 = (float*)A(2097152);
  float* y4 = (float*)A(524288);
  float* y5 = (float*)A(131072);
  uint8_t* m0 = (uint8_t*)A(16777216);
  uint8_t* m1 = (uint8_t*)A(2097152);
  uint8_t* m2 = (uint8_t*)A(262144);
  uint8_t* m3 = (uint8_t*)A(32768);
  uint8_t* m4 = (uint8_t*)A(4096);
  uint8_t* m5 = (uint8_t*)A(512);
  uint8_t* m6 = (uint8_t*)A(64);
  float* part = (float*)A(2 << 20);
  float* ss = (float*)A(4096);
  if (o > ws_size) return;  // cannot run safely

  maskA_k<<<512, 256, 0, stream>>>(msk, m0, m1, m2);
  maskB_k<<<1, 1024, 0, stream>>>(m2, m3, m4, m5, m6);

  conv0_k<<<4096, 512, 0, stream>>>(x, m0, w[0], y0, part);
  stats_k<2><<<2, 256, 0, stream>>>(part, 4096, g[0], bb[0], ss + 0);
  conv_tile_k<128, 2, 4, 8, __hip_bfloat16, __hip_bfloat16>
      <<<4096, 512, 0, stream>>>(y0, m0, m1, ss + 0, w[1], y1, part);
  stats_k<4><<<4, 256, 0, stream>>>(part, 4096, g[1], bb[1], ss + 128);
  conv_tile_k<64, 4, 8, 4, __hip_bfloat16, __hip_bfloat16>
      <<<1024, 256, 0, stream>>>(y1, m1, m2, ss + 128, w[2], y2, part);
  stats_k<8><<<8, 256, 0, stream>>>(part, 1024, g[2], bb[2], ss + 256);
  conv_s2_k<32, 8, 16, __hip_bfloat16, float>
      <<<2048, 256, 0, stream>>>(y2, m2, m3, ss + 256, w[3], y3, part);
  stats_k<16><<<16, 256, 0, stream>>>(part, 2048, g[3], bb[3], ss + 384);
  conv_s2_k<16, 16, 32, float, float>
      <<<512, 256, 0, stream>>>(y3, m3, m4, ss + 384, w[4], y4, part);
  stats_k<32><<<32, 256, 0, stream>>>(part, 512, g[4], bb[4], ss + 512);
  conv_s2_k<8, 32, 64, float, float>
      <<<128, 256, 0, stream>>>(y4, m4, m5, ss + 512, w[5], y5, part);
  pool_stats_k<<<8, 512, 0, stream>>>(y5, m5, m6, part, g[5], bb[5], (float*)d_out);
}

// Round 7
// 300.647 us; speedup vs baseline: 6.2651x; 1.0269x over previous
//
#include <hip/hip_runtime.h>
#include <hip/hip_bf16.h>
#include <stdint.h>

#define DEV __device__ __forceinline__

constexpr int BATCH = 8;

constexpr int il2(int n) { return (n <= 1) ? 0 : 1 + il2(n / 2); }

DEV float ldy(const float* p, int i) { return p[i]; }
DEV float ldy(const __hip_bfloat16* p, int i) { return __bfloat162float(p[i]); }
DEV void sty(float* p, size_t i, float v) { p[i] = v; }
DEV void sty(__hip_bfloat16* p, size_t i, float v) { p[i] = __float2bfloat16(v); }

DEV uint32_t f2bf(float v) {
  __hip_bfloat16 h = __float2bfloat16(v);
  return (uint32_t)*reinterpret_cast<uint16_t*>(&h);
}
// bf16 pair unpack: low half / high half of a u32 -> float (single shift!)
DEV float bflo(uint32_t u) {
  uint32_t t = u << 16;
  float f;
  __builtin_memcpy(&f, &t, 4);
  return f;
}
DEV float bfhi(uint32_t u) {
  uint32_t t = u & 0xffff0000u;
  float f;
  __builtin_memcpy(&f, &t, 4);
  return f;
}
constexpr uint32_t NEGINF_BF = 0xFF80u;  // bf16 -inf
// XCD-aware swizzle (bijective when nwg % 8 == 0)
DEV int xswz(int o, int nwg) { return (o & 7) * (nwg >> 3) + (o >> 3); }

// ---------------- maskA: int32 mask -> m0, m1, m2 (fused pyramid, LDS-tiled) ----------------
__global__ __launch_bounds__(256) void maskA_k(const int* __restrict__ msk,
                                               uint8_t* __restrict__ m0,
                                               uint8_t* __restrict__ m1,
                                               uint8_t* __restrict__ m2) {
  __shared__ uint8_t t0[32768];
  __shared__ uint8_t t1[4096];
  int blk = blockIdx.x;
  int bx = (blk & 3) * 32, by = ((blk >> 2) & 3) * 32, bz = ((blk >> 4) & 3) * 32, b = blk >> 6;
  int tid = threadIdx.x;
  for (int g = tid; g < 8192; g += 256) {
    int gx4 = (g & 7) * 4, gy = (g >> 3) & 31, gz = g >> 8;
    int gidx = ((b * 128 + bz + gz) * 128 + by + gy) * 128 + bx + gx4;
    int4 v = *(const int4*)(msk + gidx);
    uint32_t o = (v.x ? 1u : 0u) | (v.y ? 256u : 0u) | (v.z ? 65536u : 0u) | (v.w ? 16777216u : 0u);
    ((uint32_t*)t0)[g] = o;
    ((uint32_t*)m0)[gidx >> 2] = o;
  }
  __syncthreads();
  for (int j = tid; j < 4096; j += 256) {
    int ox = j & 15, oy = (j >> 4) & 15, oz = j >> 8;
    uint32_t act = 0;
#pragma unroll
    for (int dz = 0; dz < 2; dz++)
#pragma unroll
      for (int dy = 0; dy < 2; dy++)
        act |= *(const uint16_t*)&t0[(2 * oz + dz) * 1024 + (2 * oy + dy) * 32 + 2 * ox];
    uint8_t vv = act ? 1 : 0;
    t1[j] = vv;
    m1[((b * 64 + bz / 2 + oz) * 64 + by / 2 + oy) * 64 + bx / 2 + ox] = vv;
  }
  __syncthreads();
  for (int j = tid; j < 512; j += 256) {
    int ox = j & 7, oy = (j >> 3) & 7, oz = j >> 6;
    uint32_t act = 0;
#pragma unroll
    for (int dz = 0; dz < 2; dz++)
#pragma unroll
      for (int dy = 0; dy < 2; dy++)
        act |= *(const uint16_t*)&t1[(2 * oz + dz) * 256 + (2 * oy + dy) * 16 + 2 * ox];
    m2[((b * 32 + bz / 4 + oz) * 32 + by / 4 + oy) * 32 + bx / 4 + ox] = act ? 1 : 0;
  }
}

// ---------------- maskB: m2 -> m3, m4, m5, m6 (single block) ----------------
__global__ __launch_bounds__(1024) void maskB_k(const uint8_t* __restrict__ m2,
                                                uint8_t* __restrict__ m3,
                                                uint8_t* __restrict__ m4,
                                                uint8_t* __restrict__ m5,
                                                uint8_t* __restrict__ m6) {
  __shared__ uint8_t t3[32768];
  __shared__ uint8_t t4[4096];
  __shared__ uint8_t t5[512];
  int tid = threadIdx.x;
  for (int j = tid; j < 32768; j += 1024) {
    int ox = j & 15, oy = (j >> 4) & 15, oz = (j >> 8) & 15, b = j >> 12;
    uint32_t act = 0;
#pragma unroll
    for (int dz = 0; dz < 2; dz++)
#pragma unroll
      for (int dy = 0; dy < 2; dy++)
        act |= *(const uint16_t*)&m2[((b * 32 + 2 * oz + dz) * 32 + 2 * oy + dy) * 32 + 2 * ox];
    uint8_t v = act ? 1 : 0;
    t3[j] = v;
    m3[j] = v;
  }
  __syncthreads();
  for (int j = tid; j < 4096; j += 1024) {
    int ox = j & 7, oy = (j >> 3) & 7, oz = (j >> 6) & 7, b = j >> 9;
    uint32_t act = 0;
#pragma unroll
    for (int dz = 0; dz < 2; dz++)
#pragma unroll
      for (int dy = 0; dy < 2; dy++)
        act |= *(const uint16_t*)&t3[((b * 16 + 2 * oz + dz) * 16 + 2 * oy + dy) * 16 + 2 * ox];
    uint8_t v = act ? 1 : 0;
    t4[j] = v;
    m4[j] = v;
  }
  __syncthreads();
  if (tid < 512) {
    int j = tid;
    int ox = j & 3, oy = (j >> 2) & 3, oz = (j >> 4) & 3, b = j >> 6;
    uint32_t act = 0;
#pragma unroll
    for (int dz = 0; dz < 2; dz++)
#pragma unroll
      for (int dy = 0; dy < 2; dy++)
        act |= *(const uint16_t*)&t4[((b * 8 + 2 * oz + dz) * 8 + 2 * oy + dy) * 8 + 2 * ox];
    uint8_t v = act ? 1 : 0;
    t5[j] = v;
    m5[j] = v;
  }
  __syncthreads();
  if (tid < 64) {
    int j = tid;
    int ox = j & 1, oy = (j >> 1) & 1, oz = (j >> 2) & 1, b = j >> 3;
    uint32_t act = 0;
#pragma unroll
    for (int dz = 0; dz < 2; dz++)
#pragma unroll
      for (int dy = 0; dy < 2; dy++)
        act |= *(const uint16_t*)&t5[((b * 4 + 2 * oz + dz) * 4 + 2 * oy + dy) * 4 + 2 * ox];
    m6[j] = act ? 1 : 0;
  }
}

// ---------------- layer 0 conv: Cin=1, Cout=2, stride 1, 16^3 tile, 8 voxels/thread ----------
// y0 stores conv result at active voxels, -inf at inactive (consumer's BN+ReLU maps -inf -> 0).
__global__ __launch_bounds__(512) void conv0_k(const float* __restrict__ x,
                                               const uint8_t* __restrict__ m0,
                                               const float* __restrict__ w,  // [27][1][2]
                                               __hip_bfloat16* __restrict__ y0,
                                               float* __restrict__ partials) {
  constexpr int RS = 20, PS = 360;
  __shared__ float sx[18 * PS];
  __shared__ float sm[8][5];
  int blk = xswz(blockIdx.x, 4096);
  int tx0 = (blk & 7) * 16, ty0 = ((blk >> 3) & 7) * 16, tz0 = ((blk >> 6) & 7) * 16, b = blk >> 9;
  int tid = threadIdx.x;
  int tc = tid & 7, tb = (tid >> 3) & 7, ta = tid >> 6;
  // stage 18x18x18 halo (masked, zero-padded); 3D-mapped, division-free
#pragma unroll
  for (int sz = ta; sz < 18; sz += 8) {
    int gz = tz0 + sz - 1;
    bool okz = (unsigned)gz < 128u;
    int zoff = (b * 128 + gz) * 128;
#pragma unroll
    for (int sy = tb; sy < 18; sy += 8) {
      int gy = ty0 + sy - 1;
      bool oky = okz && ((unsigned)gy < 128u);
      int yoff = (zoff + gy) * 128;
#pragma unroll
      for (int sxx = tc; sxx < 18; sxx += 8) {
        int gx = tx0 + sxx - 1;
        float val = 0.f;
        if (oky && (unsigned)gx < 128u) {
          int gi = yoff + gx;
          uint8_t mb = m0[gi];
          float xv = x[gi];
          val = mb ? xv : 0.f;
        }
        sx[sz * PS + sy * RS + sxx] = val;
      }
    }
  }
  __syncthreads();

  int lx = tc * 2, ly = tb * 2, lz = ta * 2;
  float rg[4][4][4];
#pragma unroll
  for (int dz = 0; dz < 4; dz++)
#pragma unroll
    for (int dy = 0; dy < 4; dy++)
#pragma unroll
      for (int dx = 0; dx < 4; dx += 2) {
        float2 v = *(const float2*)&sx[(lz + dz) * PS + (ly + dy) * RS + lx + dx];
        rg[dz][dy][dx] = v.x;
        rg[dz][dy][dx + 1] = v.y;
      }

  float acc[2][2][2][2];  // [oz][oy][ox][ch]
#pragma unroll
  for (int oz = 0; oz < 2; oz++)
#pragma unroll
    for (int oy = 0; oy < 2; oy++)
#pragma unroll
      for (int ox = 0; ox < 2; ox++)
        acc[oz][oy][ox][0] = acc[oz][oy][ox][1] = 0.f;

#pragma unroll
  for (int dz = 0; dz < 3; dz++)
#pragma unroll
    for (int dy = 0; dy < 3; dy++)
#pragma unroll
      for (int dx = 0; dx < 3; dx++) {
        float w0 = w[((dz * 3 + dy) * 3 + dx) * 2];
        float w1 = w[((dz * 3 + dy) * 3 + dx) * 2 + 1];
#pragma unroll
        for (int oz = 0; oz < 2; oz++)
#pragma unroll
          for (int oy = 0; oy < 2; oy++)
#pragma unroll
            for (int ox = 0; ox < 2; ox++) {
              float s = rg[oz + dz][oy + dy][ox + dx];
              acc[oz][oy][ox][0] = fmaf(s, w0, acc[oz][oy][ox][0]);
              acc[oz][oy][ox][1] = fmaf(s, w1, acc[oz][oy][ox][1]);
            }
      }

  // store (-inf at inactive) + masked stats; mask pairs read direct from m0 (L2-hot)
  float s0 = 0.f, q0 = 0.f, s1 = 0.f, q1 = 0.f;
  int cnt = 0;
#pragma unroll
  for (int oz = 0; oz < 2; oz++)
#pragma unroll
    for (int oy = 0; oy < 2; oy++) {
      int z = tz0 + lz + oz, y = ty0 + ly + oy, xx = tx0 + lx;
      int vo = ((b * 128 + z) * 128 + y) * 128 + xx;
      uint32_t mm = *(const uint16_t*)(m0 + vo);
      uint2 st;
      if (mm & 0xff) {
        st.x = f2bf(acc[oz][oy][0][0]) | (f2bf(acc[oz][oy][0][1]) << 16);
        s0 += acc[oz][oy][0][0];
        q0 += acc[oz][oy][0][0] * acc[oz][oy][0][0];
        s1 += acc[oz][oy][0][1];
        q1 += acc[oz][oy][0][1] * acc[oz][oy][0][1];
        cnt++;
      } else {
        st.x = NEGINF_BF | (NEGINF_BF << 16);
      }
      if (mm >> 8) {
        st.y = f2bf(acc[oz][oy][1][0]) | (f2bf(acc[oz][oy][1][1]) << 16);
        s0 += acc[oz][oy][1][0];
        q0 += acc[oz][oy][1][0] * acc[oz][oy][1][0];
        s1 += acc[oz][oy][1][1];
        q1 += acc[oz][oy][1][1] * acc[oz][oy][1][1];
        cnt++;
      } else {
        st.y = NEGINF_BF | (NEGINF_BF << 16);
      }
      ((uint2*)y0)[vo >> 1] = st;
    }
  float cf = (float)cnt;
#pragma unroll
  for (int off = 32; off >= 1; off >>= 1) {
    s0 += __shfl_xor(s0, off);
    q0 += __shfl_xor(q0, off);
    s1 += __shfl_xor(s1, off);
    q1 += __shfl_xor(q1, off);
    cf += __shfl_xor(cf, off);
  }
  int wave = tid >> 6;
  if ((tid & 63) == 0) {
    sm[wave][0] = s0;
    sm[wave][1] = q0;
    sm[wave][2] = s1;
    sm[wave][3] = q1;
    sm[wave][4] = cf;
  }
  __syncthreads();
  if (tid < 5) {
    float t = 0.f;
#pragma unroll
    for (int wv = 0; wv < 8; wv++) t += sm[wv][tid];
    partials[blk * 5 + tid] = t;
  }
}

// ---------------- LDS-tiled stride-2 conv; input carries -inf sentinel (no mask reads) -------
template <int Din, int Cin, int Cout, int TZ, typename Tin, typename Tout>
__global__ __launch_bounds__(512) void conv_tile_k(const Tin* __restrict__ yin,
                                                   const uint8_t* __restrict__ mo,
                                                   const float* __restrict__ ssin,  // [2*Cin]
                                                   const float* __restrict__ w,     // [27][Cin][Cout]
                                                   Tout* __restrict__ yout,
                                                   float* __restrict__ partials) {
  constexpr int Dout = Din / 2;
  constexpr int NT = 64 * TZ;
  constexpr int IZ = 2 * TZ + 1;
  constexpr int NS = 289 * IZ;
  constexpr int TXN = Dout / 8;
  constexpr int TZN = Dout / TZ;
  constexpr int LTX = il2(TXN);
  constexpr int LTZ = il2(TZN);
  constexpr int NWG = TXN * TXN * TZN * BATCH;
  constexpr int REC = 2 * Cout + 1;
  __shared__ float sx[NS * Cin];
  __shared__ float sm[TZ][REC];

  int tid = threadIdx.x;
  int blk = xswz(blockIdx.x, NWG);
  int tx0 = (blk & (TXN - 1)) * 8;
  int ty0 = ((blk >> LTX) & (TXN - 1)) * 8;
  int tz0 = ((blk >> (2 * LTX)) & (TZN - 1)) * TZ;
  int b = blk >> (2 * LTX + LTZ);
  int tc = tid & 7, tb = (tid >> 3) & 7, ta = tid >> 6;  // ta < TZ

  float sc[Cin], sh[Cin];
#pragma unroll
  for (int ci = 0; ci < Cin; ci++) {
    sc[ci] = ssin[2 * ci];
    sh[ci] = ssin[2 * ci + 1];
  }

  int ox = 2 * tx0 - 1, oy = 2 * ty0 - 1, oz = 2 * tz0 - 1;
  // staging: 3D-mapped, division-free; BN+ReLU folded; -inf input -> 0 automatically
#pragma unroll
  for (int sz = ta; sz < IZ; sz += TZ) {
    int gz = oz + sz;
    bool okz = (unsigned)gz < (unsigned)Din;
    int zoff = (b * Din + gz) * Din;
#pragma unroll
    for (int sy = tb; sy < 17; sy += 8) {
      int gy = oy + sy;
      bool oky = okz && ((unsigned)gy < (unsigned)Din);
      int yoff = (zoff + gy) * Din;
#pragma unroll
      for (int sxx = tc; sxx < 17; sxx += 8) {
        int gx = ox + sxx;
        float v[Cin];
#pragma unroll
        for (int ci = 0; ci < Cin; ci++) v[ci] = 0.f;
        if (oky && (unsigned)gx < (unsigned)Din) {
          int gi = yoff + gx;
          float f[Cin];
          if constexpr (sizeof(Tin) == 2 && Cin == 2) {
            uint32_t rr = *(const uint32_t*)((const uint16_t*)yin + (size_t)gi * 2);
            f[0] = bflo(rr);
            f[1] = bfhi(rr);
          } else if constexpr (sizeof(Tin) == 2 && Cin == 4) {
            uint2 rr = *(const uint2*)((const uint16_t*)yin + (size_t)gi * 4);
            f[0] = bflo(rr.x);
            f[1] = bfhi(rr.x);
            f[2] = bflo(rr.y);
            f[3] = bfhi(rr.y);
          } else {
#pragma unroll
            for (int ci = 0; ci < Cin; ci++) f[ci] = ldy(yin + (size_t)gi * Cin, ci);
          }
#pragma unroll
          for (int ci = 0; ci < Cin; ci++)
            v[ci] = fmaxf(fmaf(f[ci], sc[ci], sh[ci]), 0.f);
        }
        int si = (sz * 289 + sy * 17 + sxx) * Cin;
#pragma unroll
        for (int ci = 0; ci < Cin; ci++) sx[si + ci] = v[ci];
      }
    }
  }
  __syncthreads();

  int lx = tc, ly = tb, lz = ta;
  int vo = ((b * Dout + tz0 + lz) * Dout + ty0 + ly) * Dout + tx0 + lx;
  bool act = mo[vo] != 0;
  float acc[Cout];
#pragma unroll
  for (int co = 0; co < Cout; co++) acc[co] = 0.f;
  if (act) {
    int base = ((2 * lz) * 289 + (2 * ly) * 17 + (2 * lx)) * Cin;
#pragma unroll
    for (int dz = 0; dz < 3; dz++)
#pragma unroll
      for (int dy = 0; dy < 3; dy++)
#pragma unroll
        for (int dx = 0; dx < 3; dx++) {
          int off = base + (dz * 289 + dy * 17 + dx) * Cin;
          const float* wp = w + ((dz * 3 + dy) * 3 + dx) * Cin * Cout;
#pragma unroll
          for (int ci = 0; ci < Cin; ci++) {
            float s = sx[off + ci];
#pragma unroll
            for (int co = 0; co < Cout; co++)
              acc[co] = fmaf(s, wp[ci * Cout + co], acc[co]);
          }
        }
  }
  // store: -inf at inactive
  if constexpr (sizeof(Tout) == 2) {
    uint32_t pk[Cout / 2];
    if (act) {
#pragma unroll
      for (int k = 0; k < Cout / 2; k++) pk[k] = f2bf(acc[2 * k]) | (f2bf(acc[2 * k + 1]) << 16);
    } else {
#pragma unroll
      for (int k = 0; k < Cout / 2; k++) pk[k] = NEGINF_BF | (NEGINF_BF << 16);
    }
    if constexpr (Cout == 4)
      *(uint2*)((uint16_t*)yout + (size_t)vo * 4) = *(uint2*)pk;
    else if constexpr (Cout == 8)
      *(uint4*)((uint16_t*)yout + (size_t)vo * 8) = *(uint4*)pk;
    else {
#pragma unroll
      for (int k = 0; k < Cout / 2; k++)
        *((uint32_t*)yout + (size_t)vo * (Cout / 2) + k) = pk[k];
    }
  } else {
#pragma unroll
    for (int co = 0; co < Cout; co++)
      sty(yout, (size_t)vo * Cout + co, act ? acc[co] : -INFINITY);
  }
  unsigned long long bal = __ballot(act);
  int wave = tid >> 6, lane = tid & 63;
#pragma unroll
  for (int co = 0; co < Cout; co++) {
    float s = acc[co], q = acc[co] * acc[co];
#pragma unroll
    for (int off = 32; off >= 1; off >>= 1) {
      s += __shfl_xor(s, off);
      q += __shfl_xor(q, off);
    }
    if (lane == 0) {
      sm[wave][2 * co] = s;
      sm[wave][2 * co + 1] = q;
    }
  }
  if (lane == 0) sm[wave][2 * Cout] = (float)__popcll(bal);
  __syncthreads();
  if (tid < REC) {
    float t = 0.f;
#pragma unroll
    for (int wv = 0; wv < TZ; wv++) t += sm[wv][tid];
    partials[(size_t)blk * REC + tid] = t;
  }
}

// ---------------- generic stride-2 conv (small layers); -inf sentinel input ----------------
template <int Din, int Cin, int Cout, typename Tin, typename Tout>
__global__ __launch_bounds__(256) void conv_s2_k(const Tin* __restrict__ yin,
                                                 const uint8_t* __restrict__ mo,
                                                 const float* __restrict__ ssin,
                                                 const float* __restrict__ w,
                                                 Tout* __restrict__ yout,
                                                 float* __restrict__ partials) {
  constexpr int Dout = Din / 2;
  constexpr int LD = il2(Dout);
  constexpr int LC = il2(Cout);
  constexpr int REC = 2 * Cout + 1;
  int tid = threadIdx.x;
  int lin = blockIdx.x * 256 + tid;
  int co = lin & (Cout - 1);
  int v = lin >> LC;
  int x = v & (Dout - 1);
  int y = (v >> LD) & (Dout - 1);
  int z = (v >> (2 * LD)) & (Dout - 1);
  int b = v >> (3 * LD);
  bool act = mo[v] != 0;
  float acc = 0.f;
  if (act) {
    for (int dz = 0; dz < 3; dz++) {
      int iz = 2 * z + dz - 1;
      if ((unsigned)iz >= (unsigned)Din) continue;
      for (int dy = 0; dy < 3; dy++) {
        int iy = 2 * y + dy - 1;
        if ((unsigned)iy >= (unsigned)Din) continue;
        for (int dx = 0; dx < 3; dx++) {
          int ix = 2 * x + dx - 1;
          if ((unsigned)ix >= (unsigned)Din) continue;
          int gi = ((b * Din + iz) * Din + iy) * Din + ix;
          const float* wp = w + ((dz * 3 + dy) * 3 + dx) * Cin * Cout + co;
          float f[Cin];
          if constexpr (sizeof(Tin) == 2 && Cin == 8) {
            uint4 rr = *(const uint4*)((const uint16_t*)yin + (size_t)gi * 8);
            f[0] = bflo(rr.x);
            f[1] = bfhi(rr.x);
            f[2] = bflo(rr.y);
            f[3] = bfhi(rr.y);
            f[4] = bflo(rr.z);
            f[5] = bfhi(rr.z);
            f[6] = bflo(rr.w);
            f[7] = bfhi(rr.w);
          } else {
            const Tin* yp = yin + (size_t)gi * Cin;
#pragma unroll
            for (int ci = 0; ci < Cin; ci++) f[ci] = ldy(yp, ci);
          }
#pragma unroll
          for (int ci = 0; ci < Cin; ci++) {
            float val = fmaxf(fmaf(f[ci], ssin[2 * ci], ssin[2 * ci + 1]), 0.f);
            acc = fmaf(val, wp[ci * Cout], acc);
          }
        }
      }
    }
  }
  sty(yout, (size_t)lin, act ? acc : -INFINITY);
  float s = acc, q = acc * acc;
#pragma unroll
  for (int off = 32; off >= Cout; off >>= 1) {
    s += __shfl_xor(s, off);
    q += __shfl_xor(q, off);
  }
  unsigned long long bal = __ballot(act && co == 0);
  __shared__ float sm[4][REC];
  int wave = tid >> 6, lane = tid & 63;
  if (lane < Cout) {
    sm[wave][2 * lane] = s;
    sm[wave][2 * lane + 1] = q;
  }
  if (lane == 0) sm[wave][2 * Cout] = (float)__popcll(bal);
  __syncthreads();
  if (tid < REC)
    partials[(size_t)blockIdx.x * REC + tid] = sm[0][tid] + sm[1][tid] + sm[2][tid] + sm[3][tid];
}

// ---------------- stat reduce: partials -> per-channel (scale, shift) ----------------
template <int Cout>
__global__ __launch_bounds__(256) void stats_k(const float* __restrict__ partials, int nblocks,
                                               const float* __restrict__ g,
                                               const float* __restrict__ bb,
                                               float* __restrict__ ss) {
  constexpr int REC = 2 * Cout + 1;
  int c = blockIdx.x, tid = threadIdx.x;
  float s = 0.f, q = 0.f, n = 0.f;
  for (int i = tid; i < nblocks; i += 256) {
    const float* p = partials + (size_t)i * REC;
    s += p[2 * c];
    q += p[2 * c + 1];
    n += p[2 * Cout];
  }
  __shared__ float S[256], Q[256], N[256];
  S[tid] = s;
  Q[tid] = q;
  N[tid] = n;
  __syncthreads();
  for (int st = 128; st > 0; st >>= 1) {
    if (tid < st) {
      S[tid] += S[tid + st];
      Q[tid] += Q[tid + st];
      N[tid] += N[tid + st];
    }
    __syncthreads();
  }
  if (tid == 0) {
    float cnt = fmaxf(N[0], 1.f);
    float mean = S[0] / cnt;
    float var = Q[0] / cnt - mean * mean;
    float scale = g[c] * rsqrtf(var + 1e-5f);
    ss[2 * c] = scale;
    ss[2 * c + 1] = bb[c] - mean * scale;
  }
}

// ---------------- final: fused stats<64> + sparse max pool (-inf sentinel input) -------------
__global__ __launch_bounds__(512) void pool_stats_k(const float* __restrict__ y5,
                                                    const uint8_t* __restrict__ m6,
                                                    const float* __restrict__ partials,  // 128x129
                                                    const float* __restrict__ g,
                                                    const float* __restrict__ bb,
                                                    float* __restrict__ out) {
  __shared__ float ssc[64], ssh[64];
  int b = blockIdx.x, tid = threadIdx.x;
  if (tid < 64) {
    float s = 0.f, q = 0.f, n = 0.f;
    for (int i = 0; i < 128; i++) {
      const float* p = partials + i * 129;
      s += p[2 * tid];
      q += p[2 * tid + 1];
      n += p[128];
    }
    float cnt = fmaxf(n, 1.f);
    float mean = s / cnt;
    float var = q / cnt - mean * mean;
    float scale = g[tid] * rsqrtf(var + 1e-5f);
    ssc[tid] = scale;
    ssh[tid] = bb[tid] - mean * scale;
  }
  __syncthreads();
  int c = tid & 63, s = tid >> 6;
  int qx = s & 1, qy = (s >> 1) & 1, qz = (s >> 2) & 1;
  int ov = ((b * 2 + qz) * 2 + qy) * 2 + qx;
  float scale = ssc[c], shift = ssh[c];
  float mx = 0.f;
  for (int dz = 0; dz < 3; dz++) {
    int iz = 2 * qz + dz - 1;
    if ((unsigned)iz >= 4u) continue;
    for (int dy = 0; dy < 3; dy++) {
      int iy = 2 * qy + dy - 1;
      if ((unsigned)iy >= 4u) continue;
      for (int dx = 0; dx < 3; dx++) {
        int ix = 2 * qx + dx - 1;
        if ((unsigned)ix >= 4u) continue;
        int gi = ((b * 4 + iz) * 4 + iy) * 4 + ix;
        // y5 = -inf at inactive -> BN -> -inf -> relu -> 0 (no contribution)
        float val = fmaxf(fmaf(y5[gi * 64 + c], scale, shift), 0.f);
        mx = fmaxf(mx, val);
      }
    }
  }
  // m6 gate is REQUIRED: inactive output can still see active neighbors in its 3^3 footprint
  out[ov * 64 + c] = m6[ov] ? mx : 0.f;
}

extern "C" void kernel_launch(void* const* d_in, const int* in_sizes, int n_in,
                              void* d_out, int out_size, void* d_ws, size_t ws_size,
                              hipStream_t stream) {
  const float* x = (const float*)d_in[0];
  const int* msk = (const int*)d_in[1];
  const float *w[6], *g[6], *bb[6];
  for (int i = 0; i < 6; i++) {
    w[i] = (const float*)d_in[2 + 3 * i];
    g[i] = (const float*)d_in[3 + 3 * i];
    bb[i] = (const float*)d_in[4 + 3 * i];
  }

  char* ws = (char*)d_ws;
  size_t o = 0;
  auto A = [&](size_t bytes) -> char* {
    char* p = ws + o;
    o = (o + bytes + 255) & ~(size_t)255;
    return p;
  };
  __hip_bfloat16* y0 = (__hip_bfloat16*)A(33554432 * 2);  // 64 MB
  __hip_bfloat16* y1 = (__hip_bfloat16*)A(8388608 * 2);   // 16 MB
  __hip_bfloat16* y2 = (__hip_bfloat16*)A(2097152 * 2);   // 4 MB
  float* y3 = (float*)A(2097152);
  float* y4 = (float*)A(524288);
  float* y5 = (float*)A(131072);
  uint8_t* m0 = (uint8_t*)A(16777216);
  uint8_t* m1 = (uint8_t*)A(2097152);
  uint8_t* m2 = (uint8_t*)A(262144);
  uint8_t* m3 = (uint8_t*)A(32768);
  uint8_t* m4 = (uint8_t*)A(4096);
  uint8_t* m5 = (uint8_t*)A(512);
  uint8_t* m6 = (uint8_t*)A(64);
  float* part = (float*)A(2 << 20);
  float* ss = (float*)A(4096);
  if (o > ws_size) return;  // cannot run safely

  maskA_k<<<512, 256, 0, stream>>>(msk, m0, m1, m2);
  maskB_k<<<1, 1024, 0, stream>>>(m2, m3, m4, m5, m6);

  conv0_k<<<4096, 512, 0, stream>>>(x, m0, w[0], y0, part);
  stats_k<2><<<2, 256, 0, stream>>>(part, 4096, g[0], bb[0], ss + 0);
  conv_tile_k<128, 2, 4, 8, __hip_bfloat16, __hip_bfloat16>
      <<<4096, 512, 0, stream>>>(y0, m1, ss + 0, w[1], y1, part);
  stats_k<4><<<4, 256, 0, stream>>>(part, 4096, g[1], bb[1], ss + 128);
  conv_tile_k<64, 4, 8, 4, __hip_bfloat16, __hip_bfloat16>
      <<<1024, 256, 0, stream>>>(y1, m2, ss + 128, w[2], y2, part);
  stats_k<8><<<8, 256, 0, stream>>>(part, 1024, g[2], bb[2], ss + 256);
  conv_s2_k<32, 8, 16, __hip_bfloat16, float>
      <<<2048, 256, 0, stream>>>(y2, m3, ss + 256, w[3], y3, part);
  stats_k<16><<<16, 256, 0, stream>>>(part, 2048, g[3], bb[3], ss + 384);
  conv_s2_k<16, 16, 32, float, float>
      <<<512, 256, 0, stream>>>(y3, m4, ss + 384, w[4], y4, part);
  stats_k<32><<<32, 256, 0, stream>>>(part, 512, g[4], bb[4], ss + 512);
  conv_s2_k<8, 32, 64, float, float>
      <<<128, 256, 0, stream>>>(y4, m5, ss + 512, w[5], y5, part);
  pool_stats_k<<<8, 512, 0, stream>>>(y5, m6, part, g[5], bb[5], (float*)d_out);
}

// Round 8
// 252.354 us; speedup vs baseline: 7.4641x; 1.1914x over previous
//
#include <hip/hip_runtime.h>
#include <hip/hip_bf16.h>
#include <stdint.h>

#define DEV __device__ __forceinline__

constexpr int BATCH = 8;

constexpr int il2(int n) { return (n <= 1) ? 0 : 1 + il2(n / 2); }

DEV float ldy(const float* p, int i) { return p[i]; }
DEV float ldy(const __hip_bfloat16* p, int i) { return __bfloat162float(p[i]); }
DEV void sty(float* p, size_t i, float v) { p[i] = v; }
DEV void sty(__hip_bfloat16* p, size_t i, float v) { p[i] = __float2bfloat16(v); }

DEV uint32_t f2bf(float v) {
  __hip_bfloat16 h = __float2bfloat16(v);
  return (uint32_t)*reinterpret_cast<uint16_t*>(&h);
}
// bf16 pair unpack: low half / high half of a u32 -> float (single shift!)
DEV float bflo(uint32_t u) {
  uint32_t t = u << 16;
  float f;
  __builtin_memcpy(&f, &t, 4);
  return f;
}
DEV float bfhi(uint32_t u) {
  uint32_t t = u & 0xffff0000u;
  float f;
  __builtin_memcpy(&f, &t, 4);
  return f;
}
constexpr uint32_t NEGINF_BF = 0xFF80u;  // bf16 -inf
// XCD-aware swizzle (bijective when nwg % 8 == 0)
DEV int xswz(int o, int nwg) { return (o & 7) * (nwg >> 3) + (o >> 3); }

// ---------------- maskA: int32 mask -> m0, m1, m2 (fused pyramid, LDS-tiled) ----------------
__global__ __launch_bounds__(256) void maskA_k(const int* __restrict__ msk,
                                               uint8_t* __restrict__ m0,
                                               uint8_t* __restrict__ m1,
                                               uint8_t* __restrict__ m2) {
  __shared__ uint8_t t0[32768];
  __shared__ uint8_t t1[4096];
  int blk = blockIdx.x;
  int bx = (blk & 3) * 32, by = ((blk >> 2) & 3) * 32, bz = ((blk >> 4) & 3) * 32, b = blk >> 6;
  int tid = threadIdx.x;
  for (int g = tid; g < 8192; g += 256) {
    int gx4 = (g & 7) * 4, gy = (g >> 3) & 31, gz = g >> 8;
    int gidx = ((b * 128 + bz + gz) * 128 + by + gy) * 128 + bx + gx4;
    int4 v = *(const int4*)(msk + gidx);
    uint32_t o = (v.x ? 1u : 0u) | (v.y ? 256u : 0u) | (v.z ? 65536u : 0u) | (v.w ? 16777216u : 0u);
    ((uint32_t*)t0)[g] = o;
    ((uint32_t*)m0)[gidx >> 2] = o;
  }
  __syncthreads();
  for (int j = tid; j < 4096; j += 256) {
    int ox = j & 15, oy = (j >> 4) & 15, oz = j >> 8;
    uint32_t act = 0;
#pragma unroll
    for (int dz = 0; dz < 2; dz++)
#pragma unroll
      for (int dy = 0; dy < 2; dy++)
        act |= *(const uint16_t*)&t0[(2 * oz + dz) * 1024 + (2 * oy + dy) * 32 + 2 * ox];
    uint8_t vv = act ? 1 : 0;
    t1[j] = vv;
    m1[((b * 64 + bz / 2 + oz) * 64 + by / 2 + oy) * 64 + bx / 2 + ox] = vv;
  }
  __syncthreads();
  for (int j = tid; j < 512; j += 256) {
    int ox = j & 7, oy = (j >> 3) & 7, oz = j >> 6;
    uint32_t act = 0;
#pragma unroll
    for (int dz = 0; dz < 2; dz++)
#pragma unroll
      for (int dy = 0; dy < 2; dy++)
        act |= *(const uint16_t*)&t1[(2 * oz + dz) * 256 + (2 * oy + dy) * 16 + 2 * ox];
    m2[((b * 32 + bz / 4 + oz) * 32 + by / 4 + oy) * 32 + bx / 4 + ox] = act ? 1 : 0;
  }
}

// ---------------- maskB: m2 -> m3, m4, m5, m6 (single block) ----------------
__global__ __launch_bounds__(1024) void maskB_k(const uint8_t* __restrict__ m2,
                                                uint8_t* __restrict__ m3,
                                                uint8_t* __restrict__ m4,
                                                uint8_t* __restrict__ m5,
                                                uint8_t* __restrict__ m6) {
  __shared__ uint8_t t3[32768];
  __shared__ uint8_t t4[4096];
  __shared__ uint8_t t5[512];
  int tid = threadIdx.x;
  for (int j = tid; j < 32768; j += 1024) {
    int ox = j & 15, oy = (j >> 4) & 15, oz = (j >> 8) & 15, b = j >> 12;
    uint32_t act = 0;
#pragma unroll
    for (int dz = 0; dz < 2; dz++)
#pragma unroll
      for (int dy = 0; dy < 2; dy++)
        act |= *(const uint16_t*)&m2[((b * 32 + 2 * oz + dz) * 32 + 2 * oy + dy) * 32 + 2 * ox];
    uint8_t v = act ? 1 : 0;
    t3[j] = v;
    m3[j] = v;
  }
  __syncthreads();
  for (int j = tid; j < 4096; j += 1024) {
    int ox = j & 7, oy = (j >> 3) & 7, oz = (j >> 6) & 7, b = j >> 9;
    uint32_t act = 0;
#pragma unroll
    for (int dz = 0; dz < 2; dz++)
#pragma unroll
      for (int dy = 0; dy < 2; dy++)
        act |= *(const uint16_t*)&t3[((b * 16 + 2 * oz + dz) * 16 + 2 * oy + dy) * 16 + 2 * ox];
    uint8_t v = act ? 1 : 0;
    t4[j] = v;
    m4[j] = v;
  }
  __syncthreads();
  if (tid < 512) {
    int j = tid;
    int ox = j & 3, oy = (j >> 2) & 3, oz = (j >> 4) & 3, b = j >> 6;
    uint32_t act = 0;
#pragma unroll
    for (int dz = 0; dz < 2; dz++)
#pragma unroll
      for (int dy = 0; dy < 2; dy++)
        act |= *(const uint16_t*)&t4[((b * 8 + 2 * oz + dz) * 8 + 2 * oy + dy) * 8 + 2 * ox];
    uint8_t v = act ? 1 : 0;
    t5[j] = v;
    m5[j] = v;
  }
  __syncthreads();
  if (tid < 64) {
    int j = tid;
    int ox = j & 1, oy = (j >> 1) & 1, oz = (j >> 2) & 1, b = j >> 3;
    uint32_t act = 0;
#pragma unroll
    for (int dz = 0; dz < 2; dz++)
#pragma unroll
      for (int dy = 0; dy < 2; dy++)
        act |= *(const uint16_t*)&t5[((b * 4 + 2 * oz + dz) * 4 + 2 * oy + dy) * 4 + 2 * ox];
    m6[j] = act ? 1 : 0;
  }
}

// ---------------- layer 0 conv: Cin=1, Cout=2, stride 1, 16^3 tile, 8 voxels/thread ----------
// Flat balanced staging: phase 1 issues all loads (clamped addr), phase 2 writes LDS.
__global__ __launch_bounds__(512) void conv0_k(const float* __restrict__ x,
                                               const uint8_t* __restrict__ m0,
                                               const float* __restrict__ w,  // [27][1][2]
                                               __hip_bfloat16* __restrict__ y0,
                                               float* __restrict__ partials) {
  constexpr int NSITE = 5832;  // 18^3
  constexpr int ROUNDS = 12;   // ceil(5832/512)
  __shared__ float sx[NSITE];
  __shared__ float sm[8][5];
  int blk = xswz(blockIdx.x, 4096);
  int tx0 = (blk & 7) * 16, ty0 = ((blk >> 3) & 7) * 16, tz0 = ((blk >> 6) & 7) * 16, b = blk >> 9;
  int tid = threadIdx.x;

  // phase 1: issue all staging loads
  float xv[ROUNDS];
  uint32_t mv[ROUNDS];
#pragma unroll
  for (int r = 0; r < ROUNDS; r++) {
    unsigned i = tid + r * 512;
    int sz = i / 324;
    int rr = i - sz * 324;
    int sy = rr / 18;
    int sxx = rr - sy * 18;
    int gz = tz0 + sz - 1, gy = ty0 + sy - 1, gx = tx0 + sxx - 1;
    bool in = (i < NSITE) & ((unsigned)gz < 128u) & ((unsigned)gy < 128u) & ((unsigned)gx < 128u);
    int gi = in ? ((b * 128 + gz) * 128 + gy) * 128 + gx : 0;
    uint32_t mraw = m0[gi];
    float xraw = x[gi];
    mv[r] = in ? mraw : 0u;
    xv[r] = xraw;
  }
  // phase 2: LDS writes (lane-consecutive, conflict-free)
#pragma unroll
  for (int r = 0; r < ROUNDS; r++) {
    unsigned i = tid + r * 512;
    if (i < NSITE) sx[i] = mv[r] ? xv[r] : 0.f;
  }
  __syncthreads();

  int tc = tid & 7, tb = (tid >> 3) & 7, ta = tid >> 6;
  int lx = tc * 2, ly = tb * 2, lz = ta * 2;

  // hoist stat-mask loads (L2-hot) so latency hides under the FMA block
  uint32_t mm[2][2];
#pragma unroll
  for (int oz = 0; oz < 2; oz++)
#pragma unroll
    for (int oy = 0; oy < 2; oy++) {
      int z = tz0 + lz + oz, y = ty0 + ly + oy, xx = tx0 + lx;
      mm[oz][oy] = *(const uint16_t*)(m0 + ((b * 128 + z) * 128 + y) * 128 + xx);
    }

  float rg[4][4][4];
#pragma unroll
  for (int dz = 0; dz < 4; dz++)
#pragma unroll
    for (int dy = 0; dy < 4; dy++)
#pragma unroll
      for (int dx = 0; dx < 4; dx += 2) {
        float2 v = *(const float2*)&sx[(lz + dz) * 324 + (ly + dy) * 18 + lx + dx];
        rg[dz][dy][dx] = v.x;
        rg[dz][dy][dx + 1] = v.y;
      }

  float acc[2][2][2][2];  // [oz][oy][ox][ch]
#pragma unroll
  for (int oz = 0; oz < 2; oz++)
#pragma unroll
    for (int oy = 0; oy < 2; oy++)
#pragma unroll
      for (int ox = 0; ox < 2; ox++)
        acc[oz][oy][ox][0] = acc[oz][oy][ox][1] = 0.f;

#pragma unroll
  for (int dz = 0; dz < 3; dz++)
#pragma unroll
    for (int dy = 0; dy < 3; dy++)
#pragma unroll
      for (int dx = 0; dx < 3; dx++) {
        float w0 = w[((dz * 3 + dy) * 3 + dx) * 2];
        float w1 = w[((dz * 3 + dy) * 3 + dx) * 2 + 1];
#pragma unroll
        for (int oz = 0; oz < 2; oz++)
#pragma unroll
          for (int oy = 0; oy < 2; oy++)
#pragma unroll
            for (int ox = 0; ox < 2; ox++) {
              float s = rg[oz + dz][oy + dy][ox + dx];
              acc[oz][oy][ox][0] = fmaf(s, w0, acc[oz][oy][ox][0]);
              acc[oz][oy][ox][1] = fmaf(s, w1, acc[oz][oy][ox][1]);
            }
      }

  // store (-inf at inactive) + masked stats
  float s0 = 0.f, q0 = 0.f, s1 = 0.f, q1 = 0.f;
  int cnt = 0;
#pragma unroll
  for (int oz = 0; oz < 2; oz++)
#pragma unroll
    for (int oy = 0; oy < 2; oy++) {
      int z = tz0 + lz + oz, y = ty0 + ly + oy, xx = tx0 + lx;
      int vo = ((b * 128 + z) * 128 + y) * 128 + xx;
      uint32_t m2b = mm[oz][oy];
      uint2 st;
      if (m2b & 0xff) {
        st.x = f2bf(acc[oz][oy][0][0]) | (f2bf(acc[oz][oy][0][1]) << 16);
        s0 += acc[oz][oy][0][0];
        q0 += acc[oz][oy][0][0] * acc[oz][oy][0][0];
        s1 += acc[oz][oy][0][1];
        q1 += acc[oz][oy][0][1] * acc[oz][oy][0][1];
        cnt++;
      } else {
        st.x = NEGINF_BF | (NEGINF_BF << 16);
      }
      if (m2b >> 8) {
        st.y = f2bf(acc[oz][oy][1][0]) | (f2bf(acc[oz][oy][1][1]) << 16);
        s0 += acc[oz][oy][1][0];
        q0 += acc[oz][oy][1][0] * acc[oz][oy][1][0];
        s1 += acc[oz][oy][1][1];
        q1 += acc[oz][oy][1][1] * acc[oz][oy][1][1];
        cnt++;
      } else {
        st.y = NEGINF_BF | (NEGINF_BF << 16);
      }
      ((uint2*)y0)[vo >> 1] = st;
    }
  float cf = (float)cnt;
#pragma unroll
  for (int off = 32; off >= 1; off >>= 1) {
    s0 += __shfl_xor(s0, off);
    q0 += __shfl_xor(q0, off);
    s1 += __shfl_xor(s1, off);
    q1 += __shfl_xor(q1, off);
    cf += __shfl_xor(cf, off);
  }
  int wave = tid >> 6;
  if ((tid & 63) == 0) {
    sm[wave][0] = s0;
    sm[wave][1] = q0;
    sm[wave][2] = s1;
    sm[wave][3] = q1;
    sm[wave][4] = cf;
  }
  __syncthreads();
  if (tid < 5) {
    float t = 0.f;
#pragma unroll
    for (int wv = 0; wv < 8; wv++) t += sm[wv][tid];
    partials[blk * 5 + tid] = t;
  }
}

// ---------------- LDS-tiled stride-2 conv (bf16 in); -inf sentinel; flat balanced staging ----
template <int Din, int Cin, int Cout, int TZ, typename Tin, typename Tout>
__global__ __launch_bounds__(512) void conv_tile_k(const Tin* __restrict__ yin,
                                                   const uint8_t* __restrict__ mo,
                                                   const float* __restrict__ ssin,  // [2*Cin]
                                                   const float* __restrict__ w,     // [27][Cin][Cout]
                                                   Tout* __restrict__ yout,
                                                   float* __restrict__ partials) {
  static_assert(sizeof(Tin) == 2 && (Cin == 2 || Cin == 4), "bf16 input only");
  constexpr int Dout = Din / 2;
  constexpr int NT = 64 * TZ;
  constexpr int IZ = 2 * TZ + 1;
  constexpr int NS = 289 * IZ;
  constexpr int ROUNDS = (NS + NT - 1) / NT;
  constexpr int TXN = Dout / 8;
  constexpr int TZN = Dout / TZ;
  constexpr int LTX = il2(TXN);
  constexpr int LTZ = il2(TZN);
  constexpr int NWG = TXN * TXN * TZN * BATCH;
  constexpr int REC = 2 * Cout + 1;
  __shared__ float sx[NS * Cin];
  __shared__ float sm[TZ][REC];

  int tid = threadIdx.x;
  int blk = xswz(blockIdx.x, NWG);
  int tx0 = (blk & (TXN - 1)) * 8;
  int ty0 = ((blk >> LTX) & (TXN - 1)) * 8;
  int tz0 = ((blk >> (2 * LTX)) & (TZN - 1)) * TZ;
  int b = blk >> (2 * LTX + LTZ);

  float sc[Cin], sh[Cin];
#pragma unroll
  for (int ci = 0; ci < Cin; ci++) {
    sc[ci] = ssin[2 * ci];
    sh[ci] = ssin[2 * ci + 1];
  }

  int ox = 2 * tx0 - 1, oy = 2 * ty0 - 1, oz = 2 * tz0 - 1;
  // phase 1: issue all staging loads (clamped addresses, no branches on the load)
  uint32_t xv0[ROUNDS], xv1[ROUNDS];
  uint32_t inbits = 0;
#pragma unroll
  for (int r = 0; r < ROUNDS; r++) {
    unsigned i = tid + r * NT;
    int sz = i / 289;
    int r2 = i - sz * 289;
    int sy = r2 / 17;
    int sxx = r2 - sy * 17;
    int gz = oz + sz, gy = oy + sy, gx = ox + sxx;
    bool in = (i < NS) & ((unsigned)gz < (unsigned)Din) & ((unsigned)gy < (unsigned)Din) &
              ((unsigned)gx < (unsigned)Din);
    int gi = in ? ((b * Din + gz) * Din + gy) * Din + gx : 0;
    if (in) inbits |= (1u << r);
    if constexpr (Cin == 2) {
      xv0[r] = *(const uint32_t*)((const uint16_t*)yin + (size_t)gi * 2);
    } else {
      uint2 t = *(const uint2*)((const uint16_t*)yin + (size_t)gi * 4);
      xv0[r] = t.x;
      xv1[r] = t.y;
    }
  }
  // phase 2: BN+ReLU then LDS write (-inf sentinel -> 0 automatically)
#pragma unroll
  for (int r = 0; r < ROUNDS; r++) {
    unsigned i = tid + r * NT;
    if (i >= NS) continue;
    bool in = (inbits >> r) & 1u;
    if constexpr (Cin == 2) {
      float f0 = fmaxf(fmaf(bflo(xv0[r]), sc[0], sh[0]), 0.f);
      float f1 = fmaxf(fmaf(bfhi(xv0[r]), sc[1], sh[1]), 0.f);
      sx[i * 2] = in ? f0 : 0.f;
      sx[i * 2 + 1] = in ? f1 : 0.f;
    } else {
      float f0 = fmaxf(fmaf(bflo(xv0[r]), sc[0], sh[0]), 0.f);
      float f1 = fmaxf(fmaf(bfhi(xv0[r]), sc[1], sh[1]), 0.f);
      float f2 = fmaxf(fmaf(bflo(xv1[r]), sc[2], sh[2]), 0.f);
      float f3 = fmaxf(fmaf(bfhi(xv1[r]), sc[3], sh[3]), 0.f);
      sx[i * 4] = in ? f0 : 0.f;
      sx[i * 4 + 1] = in ? f1 : 0.f;
      sx[i * 4 + 2] = in ? f2 : 0.f;
      sx[i * 4 + 3] = in ? f3 : 0.f;
    }
  }
  __syncthreads();

  int tc = tid & 7, tb = (tid >> 3) & 7, ta = tid >> 6;
  int lx = tc, ly = tb, lz = ta;
  int vo = ((b * Dout + tz0 + lz) * Dout + ty0 + ly) * Dout + tx0 + lx;
  bool act = mo[vo] != 0;
  float acc[Cout];
#pragma unroll
  for (int co = 0; co < Cout; co++) acc[co] = 0.f;
  if (act) {
    int base = ((2 * lz) * 289 + (2 * ly) * 17 + (2 * lx)) * Cin;
#pragma unroll
    for (int dz = 0; dz < 3; dz++)
#pragma unroll
      for (int dy = 0; dy < 3; dy++)
#pragma unroll
        for (int dx = 0; dx < 3; dx++) {
          int off = base + (dz * 289 + dy * 17 + dx) * Cin;
          const float* wp = w + ((dz * 3 + dy) * 3 + dx) * Cin * Cout;
#pragma unroll
          for (int ci = 0; ci < Cin; ci++) {
            float s = sx[off + ci];
#pragma unroll
            for (int co = 0; co < Cout; co++)
              acc[co] = fmaf(s, wp[ci * Cout + co], acc[co]);
          }
        }
  }
  // store: -inf at inactive
  {
    uint32_t pk[Cout / 2];
    if (act) {
#pragma unroll
      for (int k = 0; k < Cout / 2; k++) pk[k] = f2bf(acc[2 * k]) | (f2bf(acc[2 * k + 1]) << 16);
    } else {
#pragma unroll
      for (int k = 0; k < Cout / 2; k++) pk[k] = NEGINF_BF | (NEGINF_BF << 16);
    }
    if constexpr (Cout == 4)
      *(uint2*)((uint16_t*)yout + (size_t)vo * 4) = *(uint2*)pk;
    else if constexpr (Cout == 8)
      *(uint4*)((uint16_t*)yout + (size_t)vo * 8) = *(uint4*)pk;
    else {
#pragma unroll
      for (int k = 0; k < Cout / 2; k++)
        *((uint32_t*)yout + (size_t)vo * (Cout / 2) + k) = pk[k];
    }
  }
  unsigned long long bal = __ballot(act);
  int wave = tid >> 6, lane = tid & 63;
#pragma unroll
  for (int co = 0; co < Cout; co++) {
    float s = acc[co], q = acc[co] * acc[co];
#pragma unroll
    for (int off = 32; off >= 1; off >>= 1) {
      s += __shfl_xor(s, off);
      q += __shfl_xor(q, off);
    }
    if (lane == 0) {
      sm[wave][2 * co] = s;
      sm[wave][2 * co + 1] = q;
    }
  }
  if (lane == 0) sm[wave][2 * Cout] = (float)__popcll(bal);
  __syncthreads();
  if (tid < REC) {
    float t = 0.f;
#pragma unroll
    for (int wv = 0; wv < TZ; wv++) t += sm[wv][tid];
    partials[(size_t)blk * REC + tid] = t;
  }
}

// ---------------- generic stride-2 conv (small layers); -inf sentinel input ----------------
template <int Din, int Cin, int Cout, typename Tin, typename Tout>
__global__ __launch_bounds__(256) void conv_s2_k(const Tin* __restrict__ yin,
                                                 const uint8_t* __restrict__ mo,
                                                 const float* __restrict__ ssin,
                                                 const float* __restrict__ w,
                                                 Tout* __restrict__ yout,
                                                 float* __restrict__ partials) {
  constexpr int Dout = Din / 2;
  constexpr int LD = il2(Dout);
  constexpr int LC = il2(Cout);
  constexpr int REC = 2 * Cout + 1;
  int tid = threadIdx.x;
  int lin = blockIdx.x * 256 + tid;
  int co = lin & (Cout - 1);
  int v = lin >> LC;
  int x = v & (Dout - 1);
  int y = (v >> LD) & (Dout - 1);
  int z = (v >> (2 * LD)) & (Dout - 1);
  int b = v >> (3 * LD);
  bool act = mo[v] != 0;
  float acc = 0.f;
  if (act) {
    for (int dz = 0; dz < 3; dz++) {
      int iz = 2 * z + dz - 1;
      if ((unsigned)iz >= (unsigned)Din) continue;
      for (int dy = 0; dy < 3; dy++) {
        int iy = 2 * y + dy - 1;
        if ((unsigned)iy >= (unsigned)Din) continue;
        for (int dx = 0; dx < 3; dx++) {
          int ix = 2 * x + dx - 1;
          if ((unsigned)ix >= (unsigned)Din) continue;
          int gi = ((b * Din + iz) * Din + iy) * Din + ix;
          const float* wp = w + ((dz * 3 + dy) * 3 + dx) * Cin * Cout + co;
          float f[Cin];
          if constexpr (sizeof(Tin) == 2 && Cin == 8) {
            uint4 rr = *(const uint4*)((const uint16_t*)yin + (size_t)gi * 8);
            f[0] = bflo(rr.x);
            f[1] = bfhi(rr.x);
            f[2] = bflo(rr.y);
            f[3] = bfhi(rr.y);
            f[4] = bflo(rr.z);
            f[5] = bfhi(rr.z);
            f[6] = bflo(rr.w);
            f[7] = bfhi(rr.w);
          } else {
            const Tin* yp = yin + (size_t)gi * Cin;
#pragma unroll
            for (int ci = 0; ci < Cin; ci++) f[ci] = ldy(yp, ci);
          }
#pragma unroll
          for (int ci = 0; ci < Cin; ci++) {
            float val = fmaxf(fmaf(f[ci], ssin[2 * ci], ssin[2 * ci + 1]), 0.f);
            acc = fmaf(val, wp[ci * Cout], acc);
          }
        }
      }
    }
  }
  sty(yout, (size_t)lin, act ? acc : -INFINITY);
  float s = acc, q = acc * acc;
#pragma unroll
  for (int off = 32; off >= Cout; off >>= 1) {
    s += __shfl_xor(s, off);
    q += __shfl_xor(q, off);
  }
  unsigned long long bal = __ballot(act && co == 0);
  __shared__ float sm[4][REC];
  int wave = tid >> 6, lane = tid & 63;
  if (lane < Cout) {
    sm[wave][2 * lane] = s;
    sm[wave][2 * lane + 1] = q;
  }
  if (lane == 0) sm[wave][2 * Cout] = (float)__popcll(bal);
  __syncthreads();
  if (tid < REC)
    partials[(size_t)blockIdx.x * REC + tid] = sm[0][tid] + sm[1][tid] + sm[2][tid] + sm[3][tid];
}

// ---------------- stat reduce: partials -> per-channel (scale, shift) ----------------
template <int Cout>
__global__ __launch_bounds__(256) void stats_k(const float* __restrict__ partials, int nblocks,
                                               const float* __restrict__ g,
                                               const float* __restrict__ bb,
                                               float* __restrict__ ss) {
  constexpr int REC = 2 * Cout + 1;
  int c = blockIdx.x, tid = threadIdx.x;
  float s = 0.f, q = 0.f, n = 0.f;
  for (int i = tid; i < nblocks; i += 256) {
    const float* p = partials + (size_t)i * REC;
    s += p[2 * c];
    q += p[2 * c + 1];
    n += p[2 * Cout];
  }
  __shared__ float S[256], Q[256], N[256];
  S[tid] = s;
  Q[tid] = q;
  N[tid] = n;
  __syncthreads();
  for (int st = 128; st > 0; st >>= 1) {
    if (tid < st) {
      S[tid] += S[tid + st];
      Q[tid] += Q[tid + st];
      N[tid] += N[tid + st];
    }
    __syncthreads();
  }
  if (tid == 0) {
    float cnt = fmaxf(N[0], 1.f);
    float mean = S[0] / cnt;
    float var = Q[0] / cnt - mean * mean;
    float scale = g[c] * rsqrtf(var + 1e-5f);
    ss[2 * c] = scale;
    ss[2 * c + 1] = bb[c] - mean * scale;
  }
}

// ---------------- final: fused stats<64> + sparse max pool (-inf sentinel input) -------------
__global__ __launch_bounds__(512) void pool_stats_k(const float* __restrict__ y5,
                                                    const uint8_t* __restrict__ m6,
                                                    const float* __restrict__ partials,  // 128x129
                                                    const float* __restrict__ g,
                                                    const float* __restrict__ bb,
                                                    float* __restrict__ out) {
  __shared__ float ssc[64], ssh[64];
  int b = blockIdx.x, tid = threadIdx.x;
  if (tid < 64) {
    float s = 0.f, q = 0.f, n = 0.f;
    for (int i = 0; i < 128; i++) {
      const float* p = partials + i * 129;
      s += p[2 * tid];
      q += p[2 * tid + 1];
      n += p[128];
    }
    float cnt = fmaxf(n, 1.f);
    float mean = s / cnt;
    float var = q / cnt - mean * mean;
    float scale = g[tid] * rsqrtf(var + 1e-5f);
    ssc[tid] = scale;
    ssh[tid] = bb[tid] - mean * scale;
  }
  __syncthreads();
  int c = tid & 63, s = tid >> 6;
  int qx = s & 1, qy = (s >> 1) & 1, qz = (s >> 2) & 1;
  int ov = ((b * 2 + qz) * 2 + qy) * 2 + qx;
  float scale = ssc[c], shift = ssh[c];
  float mx = 0.f;
  for (int dz = 0; dz < 3; dz++) {
    int iz = 2 * qz + dz - 1;
    if ((unsigned)iz >= 4u) continue;
    for (int dy = 0; dy < 3; dy++) {
      int iy = 2 * qy + dy - 1;
      if ((unsigned)iy >= 4u) continue;
      for (int dx = 0; dx < 3; dx++) {
        int ix = 2 * qx + dx - 1;
        if ((unsigned)ix >= 4u) continue;
        int gi = ((b * 4 + iz) * 4 + iy) * 4 + ix;
        float val = fmaxf(fmaf(y5[gi * 64 + c], scale, shift), 0.f);
        mx = fmaxf(mx, val);
      }
    }
  }
  // m6 gate is REQUIRED: inactive output can still see active neighbors in its 3^3 footprint
  out[ov * 64 + c] = m6[ov] ? mx : 0.f;
}

extern "C" void kernel_launch(void* const* d_in, const int* in_sizes, int n_in,
                              void* d_out, int out_size, void* d_ws, size_t ws_size,
                              hipStream_t stream) {
  const float* x = (const float*)d_in[0];
  const int* msk = (const int*)d_in[1];
  const float *w[6], *g[6], *bb[6];
  for (int i = 0; i < 6; i++) {
    w[i] = (const float*)d_in[2 + 3 * i];
    g[i] = (const float*)d_in[3 + 3 * i];
    bb[i] = (const float*)d_in[4 + 3 * i];
  }

  char* ws = (char*)d_ws;
  size_t o = 0;
  auto A = [&](size_t bytes) -> char* {
    char* p = ws + o;
    o = (o + bytes + 255) & ~(size_t)255;
    return p;
  };
  __hip_bfloat16* y0 = (__hip_bfloat16*)A(33554432 * 2);  // 64 MB
  __hip_bfloat16* y1 = (__hip_bfloat16*)A(8388608 * 2);   // 16 MB
  __hip_bfloat16* y2 = (__hip_bfloat16*)A(2097152 * 2);   // 4 MB
  float* y3 = (float*)A(2097152);
  float* y4 = (float*)A(524288);
  float* y5 = (float*)A(131072);
  uint8_t* m0 = (uint8_t*)A(16777216);
  uint8_t* m1 = (uint8_t*)A(2097152);
  uint8_t* m2 = (uint8_t*)A(262144);
  uint8_t* m3 = (uint8_t*)A(32768);
  uint8_t* m4 = (uint8_t*)A(4096);
  uint8_t* m5 = (uint8_t*)A(512);
  uint8_t* m6 = (uint8_t*)A(64);
  float* part = (float*)A(2 << 20);
  float* ss = (float*)A(4096);
  if (o > ws_size) return;  // cannot run safely

  maskA_k<<<512, 256, 0, stream>>>(msk, m0, m1, m2);
  maskB_k<<<1, 1024, 0, stream>>>(m2, m3, m4, m5, m6);

  conv0_k<<<4096, 512, 0, stream>>>(x, m0, w[0], y0, part);
  stats_k<2><<<2, 256, 0, stream>>>(part, 4096, g[0], bb[0], ss + 0);
  conv_tile_k<128, 2, 4, 8, __hip_bfloat16, __hip_bfloat16>
      <<<4096, 512, 0, stream>>>(y0, m1, ss + 0, w[1], y1, part);
  stats_k<4><<<4, 256, 0, stream>>>(part, 4096, g[1], bb[1], ss + 128);
  conv_tile_k<64, 4, 8, 4, __hip_bfloat16, __hip_bfloat16>
      <<<1024, 256, 0, stream>>>(y1, m2, ss + 128, w[2], y2, part);
  stats_k<8><<<8, 256, 0, stream>>>(part, 1024, g[2], bb[2], ss + 256);
  conv_s2_k<32, 8, 16, __hip_bfloat16, float>
      <<<2048, 256, 0, stream>>>(y2, m3, ss + 256, w[3], y3, part);
  stats_k<16><<<16, 256, 0, stream>>>(part, 2048, g[3], bb[3], ss + 384);
  conv_s2_k<16, 16, 32, float, float>
      <<<512, 256, 0, stream>>>(y3, m4, ss + 384, w[4], y4, part);
  stats_k<32><<<32, 256, 0, stream>>>(part, 512, g[4], bb[4], ss + 512);
  conv_s2_k<8, 32, 64, float, float>
      <<<128, 256, 0, stream>>>(y4, m5, ss + 512, w[5], y5, part);
  pool_stats_k<<<8, 512, 0, stream>>>(y5, m6, part, g[5], bb[5], (float*)d_out);
}